// Round 9
// baseline (258.685 us; speedup 1.0000x reference)
//
#include <hip/hip_runtime.h>
#include <math.h>

#define BB 4
#define CC 256
#define DD 32
#define NN 4096

typedef __attribute__((ext_vector_type(8))) short short8;
typedef __attribute__((ext_vector_type(4))) float floatx4;
typedef __attribute__((ext_vector_type(16))) float floatx16;
typedef __attribute__((ext_vector_type(4))) int intx4;
typedef __attribute__((ext_vector_type(2))) int intx2;

#define SCALEF (0.17677669529663687f * 1.4426950408889634f)  // 1/sqrt(32)*log2(e)

// float -> bf16 round-to-nearest-even
__device__ __forceinline__ ushort f2bf(float f) {
    unsigned int u = __builtin_bit_cast(unsigned int, f);
    u += 0x7FFFu + ((u >> 16) & 1u);
    return (ushort)(u >> 16);
}
// pack two floats' bf16 truncations into one dword with a single v_perm_b32
__device__ __forceinline__ int pk_trunc(float a, float b) {
    return (int)__builtin_amdgcn_perm(__builtin_bit_cast(unsigned, b),
                                      __builtin_bit_cast(unsigned, a),
                                      0x07060302u);
}
__device__ __forceinline__ float fast_exp2(float x) {
#if __has_builtin(__builtin_amdgcn_exp2f)
    return __builtin_amdgcn_exp2f(x);
#else
    return exp2f(x);
#endif
}
// permlane32_swap: a'.hi <- b.lo, b'.lo <- a.hi (lo/hi = 32-lane halves)
__device__ __forceinline__ void plswap(int& a, int& b) {
#if __has_builtin(__builtin_amdgcn_permlane32_swap)
    intx2 r = __builtin_amdgcn_permlane32_swap(a, b, false, false);
    a = r[0]; b = r[1];
#else
    const int lane = threadIdx.x & 63;
    const bool hi = lane >= 32;
    int a2 = __shfl(a, lane ^ 32);
    int b2 = __shfl(b, lane ^ 32);
    int na = hi ? b2 : a;
    int nb = hi ? b : a2;
    a = na; b = nb;
#endif
}

// ---------------------------------------------------------------------------
// Kernel 0: fused prep (R5-verbatim) — weight conversion (first 144 blocks)
// + x (B,C,N) fp32 -> xT (B,N,C) bf16 transpose via 64x64 LDS tile.
// ---------------------------------------------------------------------------
#define TP 66
__global__ __launch_bounds__(256) void prep_fused(
    const float* __restrict__ x,
    const float* __restrict__ Wq, const float* __restrict__ Wk,
    const float* __restrict__ Wv, const float* __restrict__ Wp,
    ushort* __restrict__ xT, ushort* __restrict__ Wall, ushort* __restrict__ Wpb)
{
    __shared__ ushort tile[64 * TP];
    const int t = threadIdx.x;

    const int bid = (blockIdx.z * gridDim.y + blockIdx.y) * gridDim.x + blockIdx.x;
    if (bid < 144) {
        const int e = (bid * 256 + t) * 4;   // 576 rows x 256 cols
        const int row = e >> 8, col = e & 255;
        const float* src;
        float s = 1.0f;
        ushort* dst;
        int drow;
        if (row < 32)       { src = Wq + (size_t)row * CC;          s = SCALEF; dst = Wall; drow = row; }
        else if (row < 64)  { src = Wk + (size_t)(row - 32) * CC;   dst = Wall; drow = row; }
        else if (row < 320) { src = Wv + (size_t)(row - 64) * CC;   dst = Wall; drow = row; }
        else                { src = Wp + (size_t)(row - 320) * CC;  dst = Wpb;  drow = row - 320; }
        const floatx4 w = *(const floatx4*)(src + col);
        int2 d;
        d.x = pk_trunc(w[0] * s, w[1] * s);
        d.y = pk_trunc(w[2] * s, w[3] * s);
        *(int2*)(dst + (size_t)drow * CC + col) = d;
    }

    const int b = blockIdx.z;
    const int c0 = blockIdx.y * 64;
    const int n0 = blockIdx.x * 64;
    const int cl = (t >> 4) * 4;
    const int nl = (t & 15) * 4;

    const float* src = x + ((size_t)b * CC + c0 + cl) * NN + n0 + nl;
    floatx4 v[4];
    #pragma unroll
    for (int i = 0; i < 4; ++i) v[i] = *(const floatx4*)(src + (size_t)i * NN);

    #pragma unroll
    for (int j = 0; j < 4; ++j) {
        *(int*)&tile[(nl + j) * TP + cl]     = pk_trunc(v[0][j], v[1][j]);
        *(int*)&tile[(nl + j) * TP + cl + 2] = pk_trunc(v[2][j], v[3][j]);
    }
    __syncthreads();

    const int nr = t >> 2;
    const int coff = (t & 3) * 16;
    int r[8];
    #pragma unroll
    for (int u = 0; u < 8; ++u) r[u] = *(const int*)&tile[nr * TP + coff + u * 2];
    ushort* dst = xT + ((size_t)b * NN + n0 + nr) * CC + c0 + coff;
    intx4 o0 = {r[0], r[1], r[2], r[3]};
    intx4 o1 = {r[4], r[5], r[6], r[7]};
    *(intx4*)dst = o0;
    *(intx4*)(dst + 8) = o1;
}

// ---------------------------------------------------------------------------
// Kernel 1: MFMA QKV projection (R5-verbatim) — bf16 short8 loads, A from
// Wall, B from xT.
// ---------------------------------------------------------------------------
__global__ __launch_bounds__(256) void qkv_mfma(
    const ushort* __restrict__ xT, const ushort* __restrict__ Wall,
    const float* __restrict__ bq, const float* __restrict__ bk,
    const float* __restrict__ bv,
    ushort* __restrict__ qb, ushort* __restrict__ kb, ushort* __restrict__ vb)
{
    const int t = threadIdx.x;
    const int wave = t >> 6;
    const int lane = t & 63;
    const int l15 = lane & 15, qd = lane >> 4;
    const int b = blockIdx.z, mt = blockIdx.y;   // mt 0..9
    const int n0 = blockIdx.x * 128 + wave * 32;

    const ushort* arow = Wall + (size_t)(mt * 32 + l15) * CC + qd * 8;
    const ushort* brow = xT + ((size_t)b * NN + n0 + l15) * CC + qd * 8;

    floatx4 z = {0.f, 0.f, 0.f, 0.f};
    floatx4 acc[2][2];
    acc[0][0] = z; acc[0][1] = z; acc[1][0] = z; acc[1][1] = z;

    #pragma unroll
    for (int k0 = 0; k0 < CC; k0 += 32) {
        short8 af[2], bfr[2];
        af[0]  = *(const short8*)(arow + k0);
        af[1]  = *(const short8*)(arow + 16 * CC + k0);
        bfr[0] = *(const short8*)(brow + k0);
        bfr[1] = *(const short8*)(brow + 16 * CC + k0);
        #pragma unroll
        for (int fm = 0; fm < 2; ++fm)
            #pragma unroll
            for (int fn = 0; fn < 2; ++fn)
                acc[fm][fn] = __builtin_amdgcn_mfma_f32_16x16x32_bf16(af[fm], bfr[fn], acc[fm][fn], 0, 0, 0);
    }

    #pragma unroll
    for (int fm = 0; fm < 2; ++fm) {
        const int o0 = fm * 16 + qd * 4;
        if (mt == 0) {
            const floatx4 bb = *(const floatx4*)(bq + o0);
            #pragma unroll
            for (int fn = 0; fn < 2; ++fn) {
                ushort4 h;
                h.x = f2bf(acc[fm][fn][0] + bb[0] * SCALEF);
                h.y = f2bf(acc[fm][fn][1] + bb[1] * SCALEF);
                h.z = f2bf(acc[fm][fn][2] + bb[2] * SCALEF);
                h.w = f2bf(acc[fm][fn][3] + bb[3] * SCALEF);
                *(ushort4*)(qb + ((size_t)b * NN + n0 + fn * 16 + l15) * DD + o0) = h;
            }
        } else if (mt == 1) {
            const floatx4 bb = *(const floatx4*)(bk + o0);
            #pragma unroll
            for (int fn = 0; fn < 2; ++fn) {
                ushort4 h;
                h.x = f2bf(acc[fm][fn][0] + bb[0]);
                h.y = f2bf(acc[fm][fn][1] + bb[1]);
                h.z = f2bf(acc[fm][fn][2] + bb[2]);
                h.w = f2bf(acc[fm][fn][3] + bb[3]);
                *(ushort4*)(kb + ((size_t)b * NN + n0 + fn * 16 + l15) * DD + o0) = h;
            }
        } else {
            const int oc = (mt - 2) * 32 + o0;
            const floatx4 bb = *(const floatx4*)(bv + oc);
            #pragma unroll
            for (int r = 0; r < 4; ++r)
                #pragma unroll
                for (int fn = 0; fn < 2; ++fn)
                    vb[((size_t)b * CC + oc + r) * NN + n0 + fn * 16 + l15] = f2bf(acc[fm][fn][r] + bb[r]);
        }
    }
}

// ---------------------------------------------------------------------------
// Kernel 2: MFMA flash attention v9 — R8's 32x32x16 + permlane structure
// with the q-tile HALVED (32 q per block) to cut the accumulator to 64 AGPR
// and reach 3 waves/SIMD (R8 was latency-bound at 2 waves/SIMD; three
// schedule changes were null, so occupancy is the binding constraint).
// Block = 4 key-quarter waves x (32 q x 128 c); grid (8, 64, 2) = 1024
// blocks; LDS tree 33 KB -> 3 blocks/CU.  All index math / permlane wiring /
// epilogue tree: R8-verbatim with the qg loop deleted.
// ---------------------------------------------------------------------------
__global__ __launch_bounds__(256) void attn_mfma(
    const ushort* __restrict__ qb, const ushort* __restrict__ kb,
    const ushort* __restrict__ vb, ushort* __restrict__ aoT)
{
    __shared__ float red[2][4096];   // [slot][(cg*16 + r)*64 + lane]
    __shared__ float lred[2][32];    // [slot][lane&31]

    const int t = threadIdx.x;
    const int kh = t >> 6;               // key-quarter 0..3
    const int lane = t & 63;
    const int l31 = lane & 31;
    const bool hi = lane >= 32;
    const int hib = hi ? 8 : 0;
    const int slot = blockIdx.x;
    const int b = slot >> 1;
    const int qt = (slot & 1) * 64 + blockIdx.y;   // 128 q-tiles of 32 per batch
    const int q0 = qt * 32;
    const int c0 = blockIdx.z * 128;

    // Q B-frags: B[d][q], col=lane&31=q, k=d=hib+j; dh = d-half
    short8 qf[2];
    #pragma unroll
    for (int dh = 0; dh < 2; ++dh)
        qf[dh] = *(const short8*)(qb + ((size_t)b * NN + q0 + l31) * DD + dh * 16 + hib);

    // K A-frag rows (key = lane&31 within each 32-key step), V A-frag rows (c = lane&31 + cg*32)
    const ushort* krow = kb + ((size_t)b * NN + kh * 1024 + l31) * DD + hib;
    const ushort* vrow = vb + ((size_t)b * CC + c0 + l31) * (size_t)NN + kh * 1024 + hib;

    floatx16 z16 = {0.f,0.f,0.f,0.f,0.f,0.f,0.f,0.f,0.f,0.f,0.f,0.f,0.f,0.f,0.f,0.f};
    floatx16 acc[4];   // [cg]: 32q x 128c wave tile
    #pragma unroll
    for (int cg = 0; cg < 4; ++cg) acc[cg] = z16;
    float lsum = 0.f;

    for (int kt = 0; kt < 32; ++kt) {
        short8 kf0 = *(const short8*)(krow);        // d 0..15
        short8 kf1 = *(const short8*)(krow + 16);   // d 16..31
        krow += 32 * DD;
        short8 vf[4][2];
        #pragma unroll
        for (int cg = 0; cg < 4; ++cg)
            #pragma unroll
            for (int k2 = 0; k2 < 2; ++k2)
                vf[cg][k2] = *(const short8*)(vrow + (size_t)cg * 32 * NN + k2 * 16);
        vrow += 32;

        short8 ptB[2];   // [k-half]: PV B-frags
        {
            floatx16 s = __builtin_amdgcn_mfma_f32_32x32x16_bf16(kf0, qf[0], z16, 0, 0, 0);
            s = __builtin_amdgcn_mfma_f32_32x32x16_bf16(kf1, qf[1], s, 0, 0, 0);

            float e[16];
            #pragma unroll
            for (int r = 0; r < 16; ++r) e[r] = fast_exp2(s[r]);

            lsum += (((e[0]+e[1])+(e[2]+e[3]))+((e[4]+e[5])+(e[6]+e[7])))
                  + (((e[8]+e[9])+(e[10]+e[11]))+((e[12]+e[13])+(e[14]+e[15])));

            // keys 0-15 (B-frag k-half 0)
            int a0 = pk_trunc(e[0], e[1]),  b0 = pk_trunc(e[2], e[3]);
            int c0w = pk_trunc(e[4], e[5]), d0 = pk_trunc(e[6], e[7]);
            plswap(a0, c0w);
            plswap(b0, d0);
            intx4 f0 = {a0, b0, c0w, d0};
            ptB[0] = __builtin_bit_cast(short8, f0);

            // keys 16-31 (B-frag k-half 1)
            int a1 = pk_trunc(e[8], e[9]),   b1 = pk_trunc(e[10], e[11]);
            int c1 = pk_trunc(e[12], e[13]), d1 = pk_trunc(e[14], e[15]);
            plswap(a1, c1);
            plswap(b1, d1);
            intx4 f1 = {a1, b1, c1, d1};
            ptB[1] = __builtin_bit_cast(short8, f1);
        }

        __builtin_amdgcn_s_setprio(1);
        #pragma unroll
        for (int cg = 0; cg < 4; ++cg) {
            acc[cg] = __builtin_amdgcn_mfma_f32_32x32x16_bf16(vf[cg][0], ptB[0], acc[cg], 0, 0, 0);
            acc[cg] = __builtin_amdgcn_mfma_f32_32x32x16_bf16(vf[cg][1], ptB[1], acc[cg], 0, 0, 0);
        }
        __builtin_amdgcn_s_setprio(0);
    }

    // fold partner-lane key-halves (each lane summed only its 16 of 32 keys)
    lsum += __shfl(lsum, lane ^ 32);

    // ---- reduction tree over key-quarters: (0+=1, 2+=3), then 0+=2 ----
    if (kh & 1) {
        const int s = kh >> 1;
        #pragma unroll
        for (int cg = 0; cg < 4; ++cg)
            #pragma unroll
            for (int r = 0; r < 16; ++r)
                red[s][(cg * 16 + r) * 64 + lane] = acc[cg][r];
        if (!hi) lred[s][l31] = lsum;
    }
    __syncthreads();
    if (!(kh & 1)) {
        const int s = kh >> 1;
        #pragma unroll
        for (int cg = 0; cg < 4; ++cg)
            #pragma unroll
            for (int r = 0; r < 16; ++r)
                acc[cg][r] += red[s][(cg * 16 + r) * 64 + lane];
        lsum += lred[s][l31];
    }
    __syncthreads();
    if (kh == 2) {
        #pragma unroll
        for (int cg = 0; cg < 4; ++cg)
            #pragma unroll
            for (int r = 0; r < 16; ++r)
                red[0][(cg * 16 + r) * 64 + lane] = acc[cg][r];
        if (!hi) lred[0][l31] = lsum;
    }
    __syncthreads();
    if (kh == 0) {
        #pragma unroll
        for (int cg = 0; cg < 4; ++cg)
            #pragma unroll
            for (int r = 0; r < 16; ++r)
                acc[cg][r] += red[0][(cg * 16 + r) * 64 + lane];
        lsum += lred[0][l31];

        // store: D layout col=lane&31=q, row c = (r&3)+8*(r>>2)+4*hi
        const float inv = 1.0f / lsum;
        ushort* dst = aoT + ((size_t)b * NN + q0 + l31) * CC + c0;
        #pragma unroll
        for (int cg = 0; cg < 4; ++cg) {
            #pragma unroll
            for (int rq = 0; rq < 4; ++rq) {
                ushort4 h;
                h.x = f2bf(acc[cg][rq * 4 + 0] * inv);
                h.y = f2bf(acc[cg][rq * 4 + 1] * inv);
                h.z = f2bf(acc[cg][rq * 4 + 2] * inv);
                h.w = f2bf(acc[cg][rq * 4 + 3] * inv);
                *(ushort4*)(dst + cg * 32 + rq * 8 + (hi ? 4 : 0)) = h;
            }
        }
    }
}

// ---------------------------------------------------------------------------
// Kernel 3: MFMA output projection + residual (R5-verbatim, Wpb path).
// ---------------------------------------------------------------------------
__global__ __launch_bounds__(256) void proj_mfma(
    const ushort* __restrict__ aoT, const ushort* __restrict__ Wpb,
    const float* __restrict__ bp, const float* __restrict__ x,
    const float* __restrict__ gamma, float* __restrict__ out)
{
    const int t = threadIdx.x;
    const int wave = t >> 6;
    const int lane = t & 63;
    const int l15 = lane & 15;
    const int qd = lane >> 4;
    const int b = blockIdx.z;
    const int m0 = blockIdx.y * 32;
    const int n0 = blockIdx.x * 128 + wave * 32;

    floatx4 z = {0.f, 0.f, 0.f, 0.f};
    floatx4 acc[2][2];
    acc[0][0] = z; acc[0][1] = z; acc[1][0] = z; acc[1][1] = z;

    const ushort* arow = aoT + ((size_t)b * NN + n0 + l15) * CC + qd * 8;
    const ushort* wrow = Wpb + (size_t)(m0 + l15) * CC + qd * 8;

    #pragma unroll
    for (int k0 = 0; k0 < CC; k0 += 32) {
        short8 af[2], bfr[2];
        af[0]  = *(const short8*)(wrow + k0);
        af[1]  = *(const short8*)(wrow + 16 * CC + k0);
        bfr[0] = *(const short8*)(arow + k0);
        bfr[1] = *(const short8*)(arow + 16 * CC + k0);
        #pragma unroll
        for (int fm = 0; fm < 2; ++fm)
            #pragma unroll
            for (int fn = 0; fn < 2; ++fn)
                acc[fm][fn] = __builtin_amdgcn_mfma_f32_16x16x32_bf16(af[fm], bfr[fn], acc[fm][fn], 0, 0, 0);
    }

    const float g = gamma[0];
    #pragma unroll
    for (int fm = 0; fm < 2; ++fm) {
        #pragma unroll
        for (int r = 0; r < 4; ++r) {
            int m = m0 + fm * 16 + qd * 4 + r;
            float bpv = bp[m];
            #pragma unroll
            for (int fn = 0; fn < 2; ++fn) {
                size_t addr = ((size_t)b * CC + m) * NN + n0 + fn * 16 + l15;
                out[addr] = fmaf(g, acc[fm][fn][r] + bpv, x[addr]);
            }
        }
    }
}

extern "C" void kernel_launch(void* const* d_in, const int* in_sizes, int n_in,
                              void* d_out, int out_size, void* d_ws, size_t ws_size,
                              hipStream_t stream)
{
    const float* x     = (const float*)d_in[0];
    const float* Wq    = (const float*)d_in[1];
    const float* bq    = (const float*)d_in[2];
    const float* Wk    = (const float*)d_in[3];
    const float* bk    = (const float*)d_in[4];
    const float* Wv    = (const float*)d_in[5];
    const float* bv    = (const float*)d_in[6];
    const float* Wp    = (const float*)d_in[7];
    const float* bp    = (const float*)d_in[8];
    const float* gamma = (const float*)d_in[9];
    float* out = (float*)d_out;

    ushort* qbw  = (ushort*)d_ws;                        // B*N*32  bf16 = 1 MB
    ushort* kbw  = qbw + (size_t)BB * NN * DD;           // B*N*32  bf16 = 1 MB
    ushort* vbw  = kbw + (size_t)BB * NN * DD;           // B*C*N   bf16 = 8 MB
    ushort* xaoT = vbw + (size_t)BB * CC * NN;           // xT during qkv, aoT after attn (8 MB, aliased)
    ushort* Wall = xaoT + (size_t)BB * NN * CC;          // 320*256 bf16 = 160 KB
    ushort* Wpb  = Wall + (size_t)320 * CC;              // 256*256 bf16 = 128 KB

    prep_fused<<<dim3(NN / 64, CC / 64, BB), 256, 0, stream>>>(x, Wq, Wk, Wv, Wp, xaoT, Wall, Wpb);
    qkv_mfma<<<dim3(NN / 128, 10, BB), 256, 0, stream>>>(xaoT, Wall, bq, bk, bv, qbw, kbw, vbw);
    attn_mfma<<<dim3(8, 64, 2), 256, 0, stream>>>(qbw, kbw, vbw, xaoT);
    proj_mfma<<<dim3(NN / 128, CC / 32, BB), 256, 0, stream>>>(xaoT, Wpb, bp, x, gamma, out);
}

// Round 10
// 172.910 us; speedup vs baseline: 1.4961x; 1.4961x over previous
//
#include <hip/hip_runtime.h>
#include <math.h>

#define BB 4
#define CC 256
#define DD 32
#define NN 4096

typedef __attribute__((ext_vector_type(8))) short short8;
typedef __attribute__((ext_vector_type(4))) float floatx4;
typedef __attribute__((ext_vector_type(16))) float floatx16;
typedef __attribute__((ext_vector_type(4))) int intx4;
typedef __attribute__((ext_vector_type(2))) int intx2;

#define SCALEF (0.17677669529663687f * 1.4426950408889634f)  // 1/sqrt(32)*log2(e)

// float -> bf16 round-to-nearest-even
__device__ __forceinline__ ushort f2bf(float f) {
    unsigned int u = __builtin_bit_cast(unsigned int, f);
    u += 0x7FFFu + ((u >> 16) & 1u);
    return (ushort)(u >> 16);
}
// pack two floats' bf16 truncations into one dword with a single v_perm_b32
__device__ __forceinline__ int pk_trunc(float a, float b) {
    return (int)__builtin_amdgcn_perm(__builtin_bit_cast(unsigned, b),
                                      __builtin_bit_cast(unsigned, a),
                                      0x07060302u);
}
__device__ __forceinline__ float fast_exp2(float x) {
#if __has_builtin(__builtin_amdgcn_exp2f)
    return __builtin_amdgcn_exp2f(x);
#else
    return exp2f(x);
#endif
}
// permlane32_swap: a'.hi <- b.lo, b'.lo <- a.hi (lo/hi = 32-lane halves)
__device__ __forceinline__ void plswap(int& a, int& b) {
#if __has_builtin(__builtin_amdgcn_permlane32_swap)
    intx2 r = __builtin_amdgcn_permlane32_swap(a, b, false, false);
    a = r[0]; b = r[1];
#else
    const int lane = threadIdx.x & 63;
    const bool hi = lane >= 32;
    int a2 = __shfl(a, lane ^ 32);
    int b2 = __shfl(b, lane ^ 32);
    int na = hi ? b2 : a;
    int nb = hi ? b : a2;
    a = na; b = nb;
#endif
}

// ---------------------------------------------------------------------------
// Kernel 0: fused prep (R5-verbatim) — weight conversion (first 144 blocks)
// + x (B,C,N) fp32 -> xT (B,N,C) bf16 transpose via 64x64 LDS tile.
// ---------------------------------------------------------------------------
#define TP 66
__global__ __launch_bounds__(256) void prep_fused(
    const float* __restrict__ x,
    const float* __restrict__ Wq, const float* __restrict__ Wk,
    const float* __restrict__ Wv, const float* __restrict__ Wp,
    ushort* __restrict__ xT, ushort* __restrict__ Wall, ushort* __restrict__ Wpb)
{
    __shared__ ushort tile[64 * TP];
    const int t = threadIdx.x;

    const int bid = (blockIdx.z * gridDim.y + blockIdx.y) * gridDim.x + blockIdx.x;
    if (bid < 144) {
        const int e = (bid * 256 + t) * 4;   // 576 rows x 256 cols
        const int row = e >> 8, col = e & 255;
        const float* src;
        float s = 1.0f;
        ushort* dst;
        int drow;
        if (row < 32)       { src = Wq + (size_t)row * CC;          s = SCALEF; dst = Wall; drow = row; }
        else if (row < 64)  { src = Wk + (size_t)(row - 32) * CC;   dst = Wall; drow = row; }
        else if (row < 320) { src = Wv + (size_t)(row - 64) * CC;   dst = Wall; drow = row; }
        else                { src = Wp + (size_t)(row - 320) * CC;  dst = Wpb;  drow = row - 320; }
        const floatx4 w = *(const floatx4*)(src + col);
        int2 d;
        d.x = pk_trunc(w[0] * s, w[1] * s);
        d.y = pk_trunc(w[2] * s, w[3] * s);
        *(int2*)(dst + (size_t)drow * CC + col) = d;
    }

    const int b = blockIdx.z;
    const int c0 = blockIdx.y * 64;
    const int n0 = blockIdx.x * 64;
    const int cl = (t >> 4) * 4;
    const int nl = (t & 15) * 4;

    const float* src = x + ((size_t)b * CC + c0 + cl) * NN + n0 + nl;
    floatx4 v[4];
    #pragma unroll
    for (int i = 0; i < 4; ++i) v[i] = *(const floatx4*)(src + (size_t)i * NN);

    #pragma unroll
    for (int j = 0; j < 4; ++j) {
        *(int*)&tile[(nl + j) * TP + cl]     = pk_trunc(v[0][j], v[1][j]);
        *(int*)&tile[(nl + j) * TP + cl + 2] = pk_trunc(v[2][j], v[3][j]);
    }
    __syncthreads();

    const int nr = t >> 2;
    const int coff = (t & 3) * 16;
    int r[8];
    #pragma unroll
    for (int u = 0; u < 8; ++u) r[u] = *(const int*)&tile[nr * TP + coff + u * 2];
    ushort* dst = xT + ((size_t)b * NN + n0 + nr) * CC + c0 + coff;
    intx4 o0 = {r[0], r[1], r[2], r[3]};
    intx4 o1 = {r[4], r[5], r[6], r[7]};
    *(intx4*)dst = o0;
    *(intx4*)(dst + 8) = o1;
}

// ---------------------------------------------------------------------------
// Kernel 1: MFMA QKV projection — compute identical to R5; kb/vb now stored
// in MFMA-FRAGMENT-NATIVE layouts so attn's K/V loads are fully coalesced:
//   kb[b][key>>4][d>>3][key&15][d&7]   (key = token, d = qk dim 0..31)
//   vb[b][k>>4][c][k&15]               (k = token/key, c = channel)
// Write-side algebra: d = fm*16+qd*4+r -> d>>3 = fm*2+(qd>>1) (const over r),
// d&7 = (qd&1)*4+r (contiguous) so kb keeps its ushort4 store.  qb unchanged.
// ---------------------------------------------------------------------------
__global__ __launch_bounds__(256) void qkv_mfma(
    const ushort* __restrict__ xT, const ushort* __restrict__ Wall,
    const float* __restrict__ bq, const float* __restrict__ bk,
    const float* __restrict__ bv,
    ushort* __restrict__ qb, ushort* __restrict__ kb, ushort* __restrict__ vb)
{
    const int t = threadIdx.x;
    const int wave = t >> 6;
    const int lane = t & 63;
    const int l15 = lane & 15, qd = lane >> 4;
    const int b = blockIdx.z, mt = blockIdx.y;   // mt 0..9
    const int n0 = blockIdx.x * 128 + wave * 32;

    const ushort* arow = Wall + (size_t)(mt * 32 + l15) * CC + qd * 8;
    const ushort* brow = xT + ((size_t)b * NN + n0 + l15) * CC + qd * 8;

    floatx4 z = {0.f, 0.f, 0.f, 0.f};
    floatx4 acc[2][2];
    acc[0][0] = z; acc[0][1] = z; acc[1][0] = z; acc[1][1] = z;

    #pragma unroll
    for (int k0 = 0; k0 < CC; k0 += 32) {
        short8 af[2], bfr[2];
        af[0]  = *(const short8*)(arow + k0);
        af[1]  = *(const short8*)(arow + 16 * CC + k0);
        bfr[0] = *(const short8*)(brow + k0);
        bfr[1] = *(const short8*)(brow + 16 * CC + k0);
        #pragma unroll
        for (int fm = 0; fm < 2; ++fm)
            #pragma unroll
            for (int fn = 0; fn < 2; ++fn)
                acc[fm][fn] = __builtin_amdgcn_mfma_f32_16x16x32_bf16(af[fm], bfr[fn], acc[fm][fn], 0, 0, 0);
    }

    #pragma unroll
    for (int fm = 0; fm < 2; ++fm) {
        const int o0 = fm * 16 + qd * 4;
        if (mt == 0) {
            const floatx4 bb = *(const floatx4*)(bq + o0);
            #pragma unroll
            for (int fn = 0; fn < 2; ++fn) {
                ushort4 h;
                h.x = f2bf(acc[fm][fn][0] + bb[0] * SCALEF);
                h.y = f2bf(acc[fm][fn][1] + bb[1] * SCALEF);
                h.z = f2bf(acc[fm][fn][2] + bb[2] * SCALEF);
                h.w = f2bf(acc[fm][fn][3] + bb[3] * SCALEF);
                *(ushort4*)(qb + ((size_t)b * NN + n0 + fn * 16 + l15) * DD + o0) = h;
            }
        } else if (mt == 1) {
            const floatx4 bb = *(const floatx4*)(bk + o0);
            #pragma unroll
            for (int fn = 0; fn < 2; ++fn) {
                ushort4 h;
                h.x = f2bf(acc[fm][fn][0] + bb[0]);
                h.y = f2bf(acc[fm][fn][1] + bb[1]);
                h.z = f2bf(acc[fm][fn][2] + bb[2]);
                h.w = f2bf(acc[fm][fn][3] + bb[3]);
                // kb frag layout: [(n>>4)][d>>3][n&15][d&7]
                *(ushort4*)(kb + (size_t)b * NN * DD
                                 + (size_t)(n0 / 16 + fn) * 512
                                 + (fm * 2 + (qd >> 1)) * 128
                                 + l15 * 8 + (qd & 1) * 4) = h;
            }
        } else {
            const int oc0 = (mt - 2) * 32 + o0;
            const floatx4 bb = *(const floatx4*)(bv + oc0);
            #pragma unroll
            for (int r = 0; r < 4; ++r)
                #pragma unroll
                for (int fn = 0; fn < 2; ++fn)
                    // vb frag layout: [(k>>4)][c][k&15]
                    vb[(size_t)b * CC * NN
                       + (size_t)(n0 / 16 + fn) * (CC * 16)
                       + (oc0 + r) * 16 + l15] = f2bf(acc[fm][fn][r] + bb[r]);
        }
    }
}

// ---------------------------------------------------------------------------
// Kernel 2: MFMA flash attention v10 — R8 VERBATIM (64q x 128c, 32x32x16 +
// permlane, 0 bank conflicts) except K/V reads use the fragment-native
// layouts above: every K/V load is now a fully-coalesced contiguous run
// (V: 1KB/instr, 16 full lines vs 64 quarter-lines -> L2 line traffic /4;
// K: 2x512B runs -> /2).  R9 proved V line traffic is the binding resource.
// ---------------------------------------------------------------------------
__global__ __launch_bounds__(256, 2) void attn_mfma(
    const ushort* __restrict__ qb, const ushort* __restrict__ kb,
    const ushort* __restrict__ vb, ushort* __restrict__ aoT)
{
    __shared__ float red[2][8192];   // [slot][((qg*4+cg)*16 + r)*64 + lane]
    __shared__ float lred[2][64];    // [slot][qg*32 + (lane&31)]

    const int t = threadIdx.x;
    const int kh = t >> 6;               // key-quarter 0..3
    const int lane = t & 63;
    const int l31 = lane & 31;
    const bool hi = lane >= 32;
    const int hib = hi ? 8 : 0;
    const int slot = blockIdx.x;
    const int b = slot >> 1;
    const int qt = (slot & 1) * 32 + blockIdx.y;
    const int q0 = qt * 64;
    const int c0 = blockIdx.z * 128;

    // Q B-frags (qb layout unchanged): B[d][q], col=lane&31=q, k=d=hib+j
    short8 qf[2][2];
    #pragma unroll
    for (int qg = 0; qg < 2; ++qg)
        #pragma unroll
        for (int dh = 0; dh < 2; ++dh)
            qf[qg][dh] = *(const short8*)(qb + ((size_t)b * NN + q0 + qg * 32 + l31) * DD + dh * 16 + hib);

    // K frag-native: key = kh*1024 + kt*32 + l31, d = (frag)*16 + hib + j
    //   offset = b*NN*DD + (key>>4)*512 + (d>>3)*128 + (key&15)*8 + (d&7)
    const ushort* krow = kb + (size_t)b * NN * DD + (size_t)kh * 64 * 512
                            + (l31 >> 4) * 512 + (l31 & 15) * 8 + hib * 16;  // hib*16 = hi*128
    // V frag-native: k = kh*1024 + kt*32 + k2*16 + hib + j, c = c0+cg*32+l31
    //   offset = b*CC*NN + (k>>4)*(CC*16) + c*16 + (k&15)
    const ushort* vrow = vb + (size_t)b * CC * NN + (size_t)kh * 64 * (CC * 16)
                            + (c0 + l31) * 16 + hib;

    floatx16 z16 = {0.f,0.f,0.f,0.f,0.f,0.f,0.f,0.f,0.f,0.f,0.f,0.f,0.f,0.f,0.f,0.f};
    floatx16 acc[2][4];   // [qg][cg]: 64q x 128c wave tile
    #pragma unroll
    for (int qg = 0; qg < 2; ++qg)
        #pragma unroll
        for (int cg = 0; cg < 4; ++cg) acc[qg][cg] = z16;
    float lsum[2] = {0.f, 0.f};

    for (int kt = 0; kt < 32; ++kt) {
        short8 kf0 = *(const short8*)(krow);         // d 0..15
        short8 kf1 = *(const short8*)(krow + 256);   // d 16..31
        krow += 1024;                                // 2 key-blocks of 512
        short8 vf[4][2];
        #pragma unroll
        for (int cg = 0; cg < 4; ++cg)
            #pragma unroll
            for (int k2 = 0; k2 < 2; ++k2)
                vf[cg][k2] = *(const short8*)(vrow + cg * 512 + k2 * (CC * 16));
        vrow += 2 * (CC * 16);

        short8 ptB[2][2];   // [qg][k-half]: PV B-frags
        #pragma unroll
        for (int qg = 0; qg < 2; ++qg) {
            floatx16 s = __builtin_amdgcn_mfma_f32_32x32x16_bf16(kf0, qf[qg][0], z16, 0, 0, 0);
            s = __builtin_amdgcn_mfma_f32_32x32x16_bf16(kf1, qf[qg][1], s, 0, 0, 0);

            float e[16];
            #pragma unroll
            for (int r = 0; r < 16; ++r) e[r] = fast_exp2(s[r]);

            lsum[qg] += (((e[0]+e[1])+(e[2]+e[3]))+((e[4]+e[5])+(e[6]+e[7])))
                      + (((e[8]+e[9])+(e[10]+e[11]))+((e[12]+e[13])+(e[14]+e[15])));

            // keys 0-15 (B-frag k-half 0)
            int a0 = pk_trunc(e[0], e[1]),  b0 = pk_trunc(e[2], e[3]);
            int c0w = pk_trunc(e[4], e[5]), d0 = pk_trunc(e[6], e[7]);
            plswap(a0, c0w);
            plswap(b0, d0);
            intx4 f0 = {a0, b0, c0w, d0};
            ptB[qg][0] = __builtin_bit_cast(short8, f0);

            // keys 16-31 (B-frag k-half 1)
            int a1 = pk_trunc(e[8], e[9]),   b1 = pk_trunc(e[10], e[11]);
            int c1 = pk_trunc(e[12], e[13]), d1 = pk_trunc(e[14], e[15]);
            plswap(a1, c1);
            plswap(b1, d1);
            intx4 f1 = {a1, b1, c1, d1};
            ptB[qg][1] = __builtin_bit_cast(short8, f1);
        }

        __builtin_amdgcn_s_setprio(1);
        #pragma unroll
        for (int cg = 0; cg < 4; ++cg)
            #pragma unroll
            for (int qg = 0; qg < 2; ++qg) {
                acc[qg][cg] = __builtin_amdgcn_mfma_f32_32x32x16_bf16(vf[cg][0], ptB[qg][0], acc[qg][cg], 0, 0, 0);
                acc[qg][cg] = __builtin_amdgcn_mfma_f32_32x32x16_bf16(vf[cg][1], ptB[qg][1], acc[qg][cg], 0, 0, 0);
            }
        __builtin_amdgcn_s_setprio(0);
    }

    // fold partner-lane key-halves (each lane summed only its 16 of 32 keys)
    #pragma unroll
    for (int qg = 0; qg < 2; ++qg)
        lsum[qg] += __shfl(lsum[qg], lane ^ 32);

    // ---- reduction tree over key-quarters: (0+=1, 2+=3), then 0+=2 ----
    if (kh & 1) {
        const int s = kh >> 1;
        #pragma unroll
        for (int qg = 0; qg < 2; ++qg)
            #pragma unroll
            for (int cg = 0; cg < 4; ++cg)
                #pragma unroll
                for (int r = 0; r < 16; ++r)
                    red[s][((qg * 4 + cg) * 16 + r) * 64 + lane] = acc[qg][cg][r];
        if (!hi)
            #pragma unroll
            for (int qg = 0; qg < 2; ++qg) lred[s][qg * 32 + l31] = lsum[qg];
    }
    __syncthreads();
    if (!(kh & 1)) {
        const int s = kh >> 1;
        #pragma unroll
        for (int qg = 0; qg < 2; ++qg) {
            #pragma unroll
            for (int cg = 0; cg < 4; ++cg)
                #pragma unroll
                for (int r = 0; r < 16; ++r)
                    acc[qg][cg][r] += red[s][((qg * 4 + cg) * 16 + r) * 64 + lane];
            lsum[qg] += lred[s][qg * 32 + l31];
        }
    }
    __syncthreads();
    if (kh == 2) {
        #pragma unroll
        for (int qg = 0; qg < 2; ++qg)
            #pragma unroll
            for (int cg = 0; cg < 4; ++cg)
                #pragma unroll
                for (int r = 0; r < 16; ++r)
                    red[0][((qg * 4 + cg) * 16 + r) * 64 + lane] = acc[qg][cg][r];
        if (!hi)
            #pragma unroll
            for (int qg = 0; qg < 2; ++qg) lred[0][qg * 32 + l31] = lsum[qg];
    }
    __syncthreads();
    if (kh == 0) {
        #pragma unroll
        for (int qg = 0; qg < 2; ++qg) {
            #pragma unroll
            for (int cg = 0; cg < 4; ++cg)
                #pragma unroll
                for (int r = 0; r < 16; ++r)
                    acc[qg][cg][r] += red[0][((qg * 4 + cg) * 16 + r) * 64 + lane];
            lsum[qg] += lred[0][qg * 32 + l31];
        }
        // store: D layout col=lane&31=q, row c = (r&3)+8*(r>>2)+4*hi
        #pragma unroll
        for (int qg = 0; qg < 2; ++qg) {
            const float inv = 1.0f / lsum[qg];
            ushort* dst = aoT + ((size_t)b * NN + q0 + qg * 32 + l31) * CC + c0;
            #pragma unroll
            for (int cg = 0; cg < 4; ++cg) {
                #pragma unroll
                for (int rq = 0; rq < 4; ++rq) {
                    ushort4 h;
                    h.x = f2bf(acc[qg][cg][rq * 4 + 0] * inv);
                    h.y = f2bf(acc[qg][cg][rq * 4 + 1] * inv);
                    h.z = f2bf(acc[qg][cg][rq * 4 + 2] * inv);
                    h.w = f2bf(acc[qg][cg][rq * 4 + 3] * inv);
                    *(ushort4*)(dst + cg * 32 + rq * 8 + (hi ? 4 : 0)) = h;
                }
            }
        }
    }
}

// ---------------------------------------------------------------------------
// Kernel 3: MFMA output projection + residual (R5-verbatim, Wpb path).
// ---------------------------------------------------------------------------
__global__ __launch_bounds__(256) void proj_mfma(
    const ushort* __restrict__ aoT, const ushort* __restrict__ Wpb,
    const float* __restrict__ bp, const float* __restrict__ x,
    const float* __restrict__ gamma, float* __restrict__ out)
{
    const int t = threadIdx.x;
    const int wave = t >> 6;
    const int lane = t & 63;
    const int l15 = lane & 15;
    const int qd = lane >> 4;
    const int b = blockIdx.z;
    const int m0 = blockIdx.y * 32;
    const int n0 = blockIdx.x * 128 + wave * 32;

    floatx4 z = {0.f, 0.f, 0.f, 0.f};
    floatx4 acc[2][2];
    acc[0][0] = z; acc[0][1] = z; acc[1][0] = z; acc[1][1] = z;

    const ushort* arow = aoT + ((size_t)b * NN + n0 + l15) * CC + qd * 8;
    const ushort* wrow = Wpb + (size_t)(m0 + l15) * CC + qd * 8;

    #pragma unroll
    for (int k0 = 0; k0 < CC; k0 += 32) {
        short8 af[2], bfr[2];
        af[0]  = *(const short8*)(wrow + k0);
        af[1]  = *(const short8*)(wrow + 16 * CC + k0);
        bfr[0] = *(const short8*)(arow + k0);
        bfr[1] = *(const short8*)(arow + 16 * CC + k0);
        #pragma unroll
        for (int fm = 0; fm < 2; ++fm)
            #pragma unroll
            for (int fn = 0; fn < 2; ++fn)
                acc[fm][fn] = __builtin_amdgcn_mfma_f32_16x16x32_bf16(af[fm], bfr[fn], acc[fm][fn], 0, 0, 0);
    }

    const float g = gamma[0];
    #pragma unroll
    for (int fm = 0; fm < 2; ++fm) {
        #pragma unroll
        for (int r = 0; r < 4; ++r) {
            int m = m0 + fm * 16 + qd * 4 + r;
            float bpv = bp[m];
            #pragma unroll
            for (int fn = 0; fn < 2; ++fn) {
                size_t addr = ((size_t)b * CC + m) * NN + n0 + fn * 16 + l15;
                out[addr] = fmaf(g, acc[fm][fn][r] + bpv, x[addr]);
            }
        }
    }
}

extern "C" void kernel_launch(void* const* d_in, const int* in_sizes, int n_in,
                              void* d_out, int out_size, void* d_ws, size_t ws_size,
                              hipStream_t stream)
{
    const float* x     = (const float*)d_in[0];
    const float* Wq    = (const float*)d_in[1];
    const float* bq    = (const float*)d_in[2];
    const float* Wk    = (const float*)d_in[3];
    const float* bk    = (const float*)d_in[4];
    const float* Wv    = (const float*)d_in[5];
    const float* bv    = (const float*)d_in[6];
    const float* Wp    = (const float*)d_in[7];
    const float* bp    = (const float*)d_in[8];
    const float* gamma = (const float*)d_in[9];
    float* out = (float*)d_out;

    ushort* qbw  = (ushort*)d_ws;                        // B*N*32  bf16 = 1 MB
    ushort* kbw  = qbw + (size_t)BB * NN * DD;           // B*N*32  bf16 = 1 MB (frag layout)
    ushort* vbw  = kbw + (size_t)BB * NN * DD;           // B*C*N   bf16 = 8 MB (frag layout)
    ushort* xaoT = vbw + (size_t)BB * CC * NN;           // xT during qkv, aoT after attn (8 MB, aliased)
    ushort* Wall = xaoT + (size_t)BB * NN * CC;          // 320*256 bf16 = 160 KB
    ushort* Wpb  = Wall + (size_t)320 * CC;              // 256*256 bf16 = 128 KB

    prep_fused<<<dim3(NN / 64, CC / 64, BB), 256, 0, stream>>>(x, Wq, Wk, Wv, Wp, xaoT, Wall, Wpb);
    qkv_mfma<<<dim3(NN / 128, 10, BB), 256, 0, stream>>>(xaoT, Wall, bq, bk, bv, qbw, kbw, vbw);
    attn_mfma<<<dim3(8, 32, 2), 256, 0, stream>>>(qbw, kbw, vbw, xaoT);
    proj_mfma<<<dim3(NN / 128, CC / 32, BB), 256, 0, stream>>>(xaoT, Wpb, bp, x, gamma, out);
}

// Round 11
// 162.166 us; speedup vs baseline: 1.5952x; 1.0663x over previous
//
#include <hip/hip_runtime.h>
#include <math.h>

#define BB 4
#define CC 256
#define DD 32
#define NN 4096

typedef __attribute__((ext_vector_type(8))) short short8;
typedef __attribute__((ext_vector_type(4))) float floatx4;
typedef __attribute__((ext_vector_type(16))) float floatx16;
typedef __attribute__((ext_vector_type(4))) int intx4;
typedef __attribute__((ext_vector_type(2))) int intx2;

#define SCALEF (0.17677669529663687f * 1.4426950408889634f)  // 1/sqrt(32)*log2(e)

// float -> bf16 round-to-nearest-even
__device__ __forceinline__ ushort f2bf(float f) {
    unsigned int u = __builtin_bit_cast(unsigned int, f);
    u += 0x7FFFu + ((u >> 16) & 1u);
    return (ushort)(u >> 16);
}
// pack two floats' bf16 truncations into one dword with a single v_perm_b32
__device__ __forceinline__ int pk_trunc(float a, float b) {
    return (int)__builtin_amdgcn_perm(__builtin_bit_cast(unsigned, b),
                                      __builtin_bit_cast(unsigned, a),
                                      0x07060302u);
}
__device__ __forceinline__ float fast_exp2(float x) {
#if __has_builtin(__builtin_amdgcn_exp2f)
    return __builtin_amdgcn_exp2f(x);
#else
    return exp2f(x);
#endif
}
// permlane32_swap: a'.hi <- b.lo, b'.lo <- a.hi (lo/hi = 32-lane halves)
__device__ __forceinline__ void plswap(int& a, int& b) {
#if __has_builtin(__builtin_amdgcn_permlane32_swap)
    intx2 r = __builtin_amdgcn_permlane32_swap(a, b, false, false);
    a = r[0]; b = r[1];
#else
    const int lane = threadIdx.x & 63;
    const bool hi = lane >= 32;
    int a2 = __shfl(a, lane ^ 32);
    int b2 = __shfl(b, lane ^ 32);
    int na = hi ? b2 : a;
    int nb = hi ? b : a2;
    a = na; b = nb;
#endif
}

// ---------------------------------------------------------------------------
// Kernel 1: FUSED transpose + QKV projection, single-staged.
// Grid (64 n-tiles, 4 b) = 256 blocks = 1/CU, 640 thr = 10 waves.
//   (a) batch-0 blocks (bid<64) also convert Wp fp32 -> Wpb bf16 (prep's
//       verbatim Wp branch) for the proj kernel;
//   (b) threads t<256 stage x[b, 0:256, n0:n0+64] -> LDS bf16 [64n][256c]
//       (R7's PASSED staging math: pitch 264, pk_trunc packs, 4 c-passes);
//   (c) wave w (=mt 0..9) computes 32 o-rows x 64 n: A-frags converted
//       in-register from fp32 W rows (R0/R7-proven), B-frags ds_read_b128.
// Output layouts R10-VERBATIM (qb linear; kb/vb MFMA-fragment-native), so
// attn's inputs are bit-identical.  Replaces prep_fused + qkv_mfma: x read
// once, xT round-trip (24 MB) eliminated, one fewer dispatch.
// ---------------------------------------------------------------------------
#define QTP 264   // LDS pitch in ushorts (132 dwords; stride 4 banks -> <=2-way)
__global__ __launch_bounds__(640) void qkv_fused(
    const float* __restrict__ x,
    const float* __restrict__ Wq, const float* __restrict__ bq,
    const float* __restrict__ Wk, const float* __restrict__ bk,
    const float* __restrict__ Wv, const float* __restrict__ bv,
    const float* __restrict__ Wp, ushort* __restrict__ Wpb,
    ushort* __restrict__ qb, ushort* __restrict__ kb, ushort* __restrict__ vb)
{
    __shared__ ushort tile[64 * QTP];   // ~33 KB

    const int t = threadIdx.x;
    const int wave = t >> 6;                 // 0..9 = mt
    const int lane = t & 63;
    const int l15 = lane & 15, qd = lane >> 4;
    const int b = blockIdx.y;
    const int n0 = blockIdx.x * 64;
    const int mt = wave;

    // ---- (a) Wp -> Wpb conversion (batch-0 blocks only; prep-verbatim) ----
    const int bid = blockIdx.y * gridDim.x + blockIdx.x;
    if (bid < 64 && t < 256) {
        const int e = (bid * 256 + t) * 4;   // 64 blocks * 1024 = 256*256
        const int row = e >> 8, col = e & 255;
        const floatx4 w = *(const floatx4*)(Wp + (size_t)row * CC + col);
        int2 d;
        d.x = pk_trunc(w[0], w[1]);
        d.y = pk_trunc(w[2], w[3]);
        *(int2*)(Wpb + (size_t)row * CC + col) = d;
    }

    // ---- (b) stage x slice -> LDS bf16 [n][c] (R7-verbatim math) ----
    if (t < 256) {
        const int cl = (t >> 4) * 4;   // 4 c-rows per thread
        const int nl = (t & 15) * 4;   // 4 n-cols per thread
        #pragma unroll
        for (int p = 0; p < 4; ++p) {
            const int cp = p * 64;
            const float* src = x + ((size_t)b * CC + cp + cl) * NN + n0 + nl;
            floatx4 v[4];
            #pragma unroll
            for (int i = 0; i < 4; ++i) v[i] = *(const floatx4*)(src + (size_t)i * NN);
            #pragma unroll
            for (int j = 0; j < 4; ++j) {
                *(int*)&tile[(nl + j) * QTP + cp + cl]     = pk_trunc(v[0][j], v[1][j]);
                *(int*)&tile[(nl + j) * QTP + cp + cl + 2] = pk_trunc(v[2][j], v[3][j]);
            }
        }
    }
    __syncthreads();

    // ---- (c) per-wave GEMM: A = W rows (fp32, converted in-register) ----
    const float* wr[2];
    if (mt == 0) {
        wr[0] = Wq + (size_t)l15 * CC;
        wr[1] = Wq + (size_t)(16 + l15) * CC;
    } else if (mt == 1) {
        wr[0] = Wk + (size_t)l15 * CC;
        wr[1] = Wk + (size_t)(16 + l15) * CC;
    } else {
        wr[0] = Wv + (size_t)((mt - 2) * 32 + l15) * CC;
        wr[1] = Wv + (size_t)((mt - 2) * 32 + 16 + l15) * CC;
    }

    floatx4 z = {0.f, 0.f, 0.f, 0.f};
    floatx4 acc[2][4];   // [fm][fn]: 32 o x 64 n
    #pragma unroll
    for (int fm = 0; fm < 2; ++fm)
        #pragma unroll
        for (int fn = 0; fn < 4; ++fn) acc[fm][fn] = z;

    #pragma unroll
    for (int k0 = 0; k0 < CC; k0 += 32) {
        short8 af[2], bfr[4];
        #pragma unroll
        for (int f = 0; f < 2; ++f) {
            const float* p = wr[f] + k0 + qd * 8;
            float w[8];
            #pragma unroll
            for (int j = 0; j < 8; ++j) w[j] = p[j];
            if (mt == 0) {
                #pragma unroll
                for (int j = 0; j < 8; ++j) w[j] *= SCALEF;
            }
            intx4 d;
            d[0] = pk_trunc(w[0], w[1]); d[1] = pk_trunc(w[2], w[3]);
            d[2] = pk_trunc(w[4], w[5]); d[3] = pk_trunc(w[6], w[7]);
            af[f] = __builtin_bit_cast(short8, d);
        }
        #pragma unroll
        for (int fn = 0; fn < 4; ++fn)
            bfr[fn] = *(const short8*)&tile[(fn * 16 + l15) * QTP + k0 + qd * 8];
        #pragma unroll
        for (int fm = 0; fm < 2; ++fm)
            #pragma unroll
            for (int fn = 0; fn < 4; ++fn)
                acc[fm][fn] = __builtin_amdgcn_mfma_f32_16x16x32_bf16(af[fm], bfr[fn], acc[fm][fn], 0, 0, 0);
    }

    // ---- store (R10-verbatim layouts, fn extended 0..3) ----
    #pragma unroll
    for (int fm = 0; fm < 2; ++fm) {
        const int o0 = fm * 16 + qd * 4;
        if (mt == 0) {
            const floatx4 bb = *(const floatx4*)(bq + o0);
            #pragma unroll
            for (int fn = 0; fn < 4; ++fn) {
                ushort4 h;
                h.x = f2bf(acc[fm][fn][0] + bb[0] * SCALEF);
                h.y = f2bf(acc[fm][fn][1] + bb[1] * SCALEF);
                h.z = f2bf(acc[fm][fn][2] + bb[2] * SCALEF);
                h.w = f2bf(acc[fm][fn][3] + bb[3] * SCALEF);
                *(ushort4*)(qb + ((size_t)b * NN + n0 + fn * 16 + l15) * DD + o0) = h;
            }
        } else if (mt == 1) {
            const floatx4 bb = *(const floatx4*)(bk + o0);
            #pragma unroll
            for (int fn = 0; fn < 4; ++fn) {
                ushort4 h;
                h.x = f2bf(acc[fm][fn][0] + bb[0]);
                h.y = f2bf(acc[fm][fn][1] + bb[1]);
                h.z = f2bf(acc[fm][fn][2] + bb[2]);
                h.w = f2bf(acc[fm][fn][3] + bb[3]);
                // kb frag layout: [(n>>4)][d>>3][n&15][d&7]
                *(ushort4*)(kb + (size_t)b * NN * DD
                                 + (size_t)(n0 / 16 + fn) * 512
                                 + (fm * 2 + (qd >> 1)) * 128
                                 + l15 * 8 + (qd & 1) * 4) = h;
            }
        } else {
            const int oc0 = (mt - 2) * 32 + o0;
            const floatx4 bb = *(const floatx4*)(bv + oc0);
            #pragma unroll
            for (int r = 0; r < 4; ++r)
                #pragma unroll
                for (int fn = 0; fn < 4; ++fn)
                    // vb frag layout: [(k>>4)][c][k&15]
                    vb[(size_t)b * CC * NN
                       + (size_t)(n0 / 16 + fn) * (CC * 16)
                       + (oc0 + r) * 16 + l15] = f2bf(acc[fm][fn][r] + bb[r]);
        }
    }
}

// ---------------------------------------------------------------------------
// Kernel 2: MFMA flash attention (R10-VERBATIM) — 64q x 128c, 32x32x16 +
// permlane softmax transpose, fragment-native coalesced K/V reads.
// ---------------------------------------------------------------------------
__global__ __launch_bounds__(256, 2) void attn_mfma(
    const ushort* __restrict__ qb, const ushort* __restrict__ kb,
    const ushort* __restrict__ vb, ushort* __restrict__ aoT)
{
    __shared__ float red[2][8192];   // [slot][((qg*4+cg)*16 + r)*64 + lane]
    __shared__ float lred[2][64];    // [slot][qg*32 + (lane&31)]

    const int t = threadIdx.x;
    const int kh = t >> 6;               // key-quarter 0..3
    const int lane = t & 63;
    const int l31 = lane & 31;
    const bool hi = lane >= 32;
    const int hib = hi ? 8 : 0;
    const int slot = blockIdx.x;
    const int b = slot >> 1;
    const int qt = (slot & 1) * 32 + blockIdx.y;
    const int q0 = qt * 64;
    const int c0 = blockIdx.z * 128;

    // Q B-frags (qb layout unchanged): B[d][q], col=lane&31=q, k=d=hib+j
    short8 qf[2][2];
    #pragma unroll
    for (int qg = 0; qg < 2; ++qg)
        #pragma unroll
        for (int dh = 0; dh < 2; ++dh)
            qf[qg][dh] = *(const short8*)(qb + ((size_t)b * NN + q0 + qg * 32 + l31) * DD + dh * 16 + hib);

    // K frag-native: key = kh*1024 + kt*32 + l31, d = (frag)*16 + hib + j
    const ushort* krow = kb + (size_t)b * NN * DD + (size_t)kh * 64 * 512
                            + (l31 >> 4) * 512 + (l31 & 15) * 8 + hib * 16;  // hib*16 = hi*128
    // V frag-native: k = kh*1024 + kt*32 + k2*16 + hib + j, c = c0+cg*32+l31
    const ushort* vrow = vb + (size_t)b * CC * NN + (size_t)kh * 64 * (CC * 16)
                            + (c0 + l31) * 16 + hib;

    floatx16 z16 = {0.f,0.f,0.f,0.f,0.f,0.f,0.f,0.f,0.f,0.f,0.f,0.f,0.f,0.f,0.f,0.f};
    floatx16 acc[2][4];   // [qg][cg]: 64q x 128c wave tile
    #pragma unroll
    for (int qg = 0; qg < 2; ++qg)
        #pragma unroll
        for (int cg = 0; cg < 4; ++cg) acc[qg][cg] = z16;
    float lsum[2] = {0.f, 0.f};

    for (int kt = 0; kt < 32; ++kt) {
        short8 kf0 = *(const short8*)(krow);         // d 0..15
        short8 kf1 = *(const short8*)(krow + 256);   // d 16..31
        krow += 1024;                                // 2 key-blocks of 512
        short8 vf[4][2];
        #pragma unroll
        for (int cg = 0; cg < 4; ++cg)
            #pragma unroll
            for (int k2 = 0; k2 < 2; ++k2)
                vf[cg][k2] = *(const short8*)(vrow + cg * 512 + k2 * (CC * 16));
        vrow += 2 * (CC * 16);

        short8 ptB[2][2];   // [qg][k-half]: PV B-frags
        #pragma unroll
        for (int qg = 0; qg < 2; ++qg) {
            floatx16 s = __builtin_amdgcn_mfma_f32_32x32x16_bf16(kf0, qf[qg][0], z16, 0, 0, 0);
            s = __builtin_amdgcn_mfma_f32_32x32x16_bf16(kf1, qf[qg][1], s, 0, 0, 0);

            float e[16];
            #pragma unroll
            for (int r = 0; r < 16; ++r) e[r] = fast_exp2(s[r]);

            lsum[qg] += (((e[0]+e[1])+(e[2]+e[3]))+((e[4]+e[5])+(e[6]+e[7])))
                      + (((e[8]+e[9])+(e[10]+e[11]))+((e[12]+e[13])+(e[14]+e[15])));

            // keys 0-15 (B-frag k-half 0)
            int a0 = pk_trunc(e[0], e[1]),  b0 = pk_trunc(e[2], e[3]);
            int c0w = pk_trunc(e[4], e[5]), d0 = pk_trunc(e[6], e[7]);
            plswap(a0, c0w);
            plswap(b0, d0);
            intx4 f0 = {a0, b0, c0w, d0};
            ptB[qg][0] = __builtin_bit_cast(short8, f0);

            // keys 16-31 (B-frag k-half 1)
            int a1 = pk_trunc(e[8], e[9]),   b1 = pk_trunc(e[10], e[11]);
            int c1 = pk_trunc(e[12], e[13]), d1 = pk_trunc(e[14], e[15]);
            plswap(a1, c1);
            plswap(b1, d1);
            intx4 f1 = {a1, b1, c1, d1};
            ptB[qg][1] = __builtin_bit_cast(short8, f1);
        }

        __builtin_amdgcn_s_setprio(1);
        #pragma unroll
        for (int cg = 0; cg < 4; ++cg)
            #pragma unroll
            for (int qg = 0; qg < 2; ++qg) {
                acc[qg][cg] = __builtin_amdgcn_mfma_f32_32x32x16_bf16(vf[cg][0], ptB[qg][0], acc[qg][cg], 0, 0, 0);
                acc[qg][cg] = __builtin_amdgcn_mfma_f32_32x32x16_bf16(vf[cg][1], ptB[qg][1], acc[qg][cg], 0, 0, 0);
            }
        __builtin_amdgcn_s_setprio(0);
    }

    // fold partner-lane key-halves (each lane summed only its 16 of 32 keys)
    #pragma unroll
    for (int qg = 0; qg < 2; ++qg)
        lsum[qg] += __shfl(lsum[qg], lane ^ 32);

    // ---- reduction tree over key-quarters: (0+=1, 2+=3), then 0+=2 ----
    if (kh & 1) {
        const int s = kh >> 1;
        #pragma unroll
        for (int qg = 0; qg < 2; ++qg)
            #pragma unroll
            for (int cg = 0; cg < 4; ++cg)
                #pragma unroll
                for (int r = 0; r < 16; ++r)
                    red[s][((qg * 4 + cg) * 16 + r) * 64 + lane] = acc[qg][cg][r];
        if (!hi)
            #pragma unroll
            for (int qg = 0; qg < 2; ++qg) lred[s][qg * 32 + l31] = lsum[qg];
    }
    __syncthreads();
    if (!(kh & 1)) {
        const int s = kh >> 1;
        #pragma unroll
        for (int qg = 0; qg < 2; ++qg) {
            #pragma unroll
            for (int cg = 0; cg < 4; ++cg)
                #pragma unroll
                for (int r = 0; r < 16; ++r)
                    acc[qg][cg][r] += red[s][((qg * 4 + cg) * 16 + r) * 64 + lane];
            lsum[qg] += lred[s][qg * 32 + l31];
        }
    }
    __syncthreads();
    if (kh == 2) {
        #pragma unroll
        for (int qg = 0; qg < 2; ++qg)
            #pragma unroll
            for (int cg = 0; cg < 4; ++cg)
                #pragma unroll
                for (int r = 0; r < 16; ++r)
                    red[0][((qg * 4 + cg) * 16 + r) * 64 + lane] = acc[qg][cg][r];
        if (!hi)
            #pragma unroll
            for (int qg = 0; qg < 2; ++qg) lred[0][qg * 32 + l31] = lsum[qg];
    }
    __syncthreads();
    if (kh == 0) {
        #pragma unroll
        for (int qg = 0; qg < 2; ++qg) {
            #pragma unroll
            for (int cg = 0; cg < 4; ++cg)
                #pragma unroll
                for (int r = 0; r < 16; ++r)
                    acc[qg][cg][r] += red[0][((qg * 4 + cg) * 16 + r) * 64 + lane];
            lsum[qg] += lred[0][qg * 32 + l31];
        }
        // store: D layout col=lane&31=q, row c = (r&3)+8*(r>>2)+4*hi
        #pragma unroll
        for (int qg = 0; qg < 2; ++qg) {
            const float inv = 1.0f / lsum[qg];
            ushort* dst = aoT + ((size_t)b * NN + q0 + qg * 32 + l31) * CC + c0;
            #pragma unroll
            for (int cg = 0; cg < 4; ++cg) {
                #pragma unroll
                for (int rq = 0; rq < 4; ++rq) {
                    ushort4 h;
                    h.x = f2bf(acc[qg][cg][rq * 4 + 0] * inv);
                    h.y = f2bf(acc[qg][cg][rq * 4 + 1] * inv);
                    h.z = f2bf(acc[qg][cg][rq * 4 + 2] * inv);
                    h.w = f2bf(acc[qg][cg][rq * 4 + 3] * inv);
                    *(ushort4*)(dst + cg * 32 + rq * 8 + (hi ? 4 : 0)) = h;
                }
            }
        }
    }
}

// ---------------------------------------------------------------------------
// Kernel 3: MFMA output projection + residual (R10-verbatim, Wpb path).
// ---------------------------------------------------------------------------
__global__ __launch_bounds__(256) void proj_mfma(
    const ushort* __restrict__ aoT, const ushort* __restrict__ Wpb,
    const float* __restrict__ bp, const float* __restrict__ x,
    const float* __restrict__ gamma, float* __restrict__ out)
{
    const int t = threadIdx.x;
    const int wave = t >> 6;
    const int lane = t & 63;
    const int l15 = lane & 15;
    const int qd = lane >> 4;
    const int b = blockIdx.z;
    const int m0 = blockIdx.y * 32;
    const int n0 = blockIdx.x * 128 + wave * 32;

    floatx4 z = {0.f, 0.f, 0.f, 0.f};
    floatx4 acc[2][2];
    acc[0][0] = z; acc[0][1] = z; acc[1][0] = z; acc[1][1] = z;

    const ushort* arow = aoT + ((size_t)b * NN + n0 + l15) * CC + qd * 8;
    const ushort* wrow = Wpb + (size_t)(m0 + l15) * CC + qd * 8;

    #pragma unroll
    for (int k0 = 0; k0 < CC; k0 += 32) {
        short8 af[2], bfr[2];
        af[0]  = *(const short8*)(wrow + k0);
        af[1]  = *(const short8*)(wrow + 16 * CC + k0);
        bfr[0] = *(const short8*)(arow + k0);
        bfr[1] = *(const short8*)(arow + 16 * CC + k0);
        #pragma unroll
        for (int fm = 0; fm < 2; ++fm)
            #pragma unroll
            for (int fn = 0; fn < 2; ++fn)
                acc[fm][fn] = __builtin_amdgcn_mfma_f32_16x16x32_bf16(af[fm], bfr[fn], acc[fm][fn], 0, 0, 0);
    }

    const float g = gamma[0];
    #pragma unroll
    for (int fm = 0; fm < 2; ++fm) {
        #pragma unroll
        for (int r = 0; r < 4; ++r) {
            int m = m0 + fm * 16 + qd * 4 + r;
            float bpv = bp[m];
            #pragma unroll
            for (int fn = 0; fn < 2; ++fn) {
                size_t addr = ((size_t)b * CC + m) * NN + n0 + fn * 16 + l15;
                out[addr] = fmaf(g, acc[fm][fn][r] + bpv, x[addr]);
            }
        }
    }
}

extern "C" void kernel_launch(void* const* d_in, const int* in_sizes, int n_in,
                              void* d_out, int out_size, void* d_ws, size_t ws_size,
                              hipStream_t stream)
{
    const float* x     = (const float*)d_in[0];
    const float* Wq    = (const float*)d_in[1];
    const float* bq    = (const float*)d_in[2];
    const float* Wk    = (const float*)d_in[3];
    const float* bk    = (const float*)d_in[4];
    const float* Wv    = (const float*)d_in[5];
    const float* bv    = (const float*)d_in[6];
    const float* Wp    = (const float*)d_in[7];
    const float* bp    = (const float*)d_in[8];
    const float* gamma = (const float*)d_in[9];
    float* out = (float*)d_out;

    ushort* qbw = (ushort*)d_ws;                        // B*N*32  bf16 = 1 MB
    ushort* kbw = qbw + (size_t)BB * NN * DD;           // B*N*32  bf16 = 1 MB (frag layout)
    ushort* vbw = kbw + (size_t)BB * NN * DD;           // B*C*N   bf16 = 8 MB (frag layout)
    ushort* aoT = vbw + (size_t)BB * CC * NN;           // B*N*C   bf16 = 8 MB
    ushort* Wpb = aoT + (size_t)BB * NN * CC;           // 256*256 bf16 = 128 KB

    qkv_fused<<<dim3(NN / 64, BB), 640, 0, stream>>>(x, Wq, bq, Wk, bk, Wv, bv, Wp, Wpb, qbw, kbw, vbw);
    attn_mfma<<<dim3(8, 32, 2), 256, 0, stream>>>(qbw, kbw, vbw, aoT);
    proj_mfma<<<dim3(NN / 128, CC / 32, BB), 256, 0, stream>>>(aoT, Wpb, bp, x, gamma, out);
}

// Round 12
// 152.873 us; speedup vs baseline: 1.6922x; 1.0608x over previous
//
#include <hip/hip_runtime.h>
#include <math.h>

#define BB 4
#define CC 256
#define DD 32
#define NN 4096

typedef __attribute__((ext_vector_type(8))) short short8;
typedef __attribute__((ext_vector_type(4))) float floatx4;
typedef __attribute__((ext_vector_type(16))) float floatx16;
typedef __attribute__((ext_vector_type(4))) int intx4;
typedef __attribute__((ext_vector_type(2))) int intx2;

#define SCALEF (0.17677669529663687f * 1.4426950408889634f)  // 1/sqrt(32)*log2(e)

// float -> bf16 round-to-nearest-even
__device__ __forceinline__ ushort f2bf(float f) {
    unsigned int u = __builtin_bit_cast(unsigned int, f);
    u += 0x7FFFu + ((u >> 16) & 1u);
    return (ushort)(u >> 16);
}
// pack two floats' bf16 truncations into one dword with a single v_perm_b32
__device__ __forceinline__ int pk_trunc(float a, float b) {
    return (int)__builtin_amdgcn_perm(__builtin_bit_cast(unsigned, b),
                                      __builtin_bit_cast(unsigned, a),
                                      0x07060302u);
}
__device__ __forceinline__ float fast_exp2(float x) {
#if __has_builtin(__builtin_amdgcn_exp2f)
    return __builtin_amdgcn_exp2f(x);
#else
    return exp2f(x);
#endif
}
// permlane32_swap: a'.hi <- b.lo, b'.lo <- a.hi (lo/hi = 32-lane halves)
__device__ __forceinline__ void plswap(int& a, int& b) {
#if __has_builtin(__builtin_amdgcn_permlane32_swap)
    intx2 r = __builtin_amdgcn_permlane32_swap(a, b, false, false);
    a = r[0]; b = r[1];
#else
    const int lane = threadIdx.x & 63;
    const bool hi = lane >= 32;
    int a2 = __shfl(a, lane ^ 32);
    int b2 = __shfl(b, lane ^ 32);
    int na = hi ? b2 : a;
    int nb = hi ? b : a2;
    a = na; b = nb;
#endif
}

// ---------------------------------------------------------------------------
// Kernel 1: FUSED transpose + QKV projection (R11 structure), two changes:
//   (i)  staging spread over 512 threads (was 256; 384 sat idle),
//   (ii) Wp -> Wpb conversion now writes FRAGMENT-NATIVE [c>>3][m][c&7]
//        so proj's A-loads are contiguous (was 512B-stride 4x-line gather).
// Output layouts for qb/kb/vb R10-verbatim (attn inputs bit-identical).
// ---------------------------------------------------------------------------
#define QTP 264   // LDS pitch in ushorts (132 dwords; stride 4 banks -> <=2-way)
__global__ __launch_bounds__(640) void qkv_fused(
    const float* __restrict__ x,
    const float* __restrict__ Wq, const float* __restrict__ bq,
    const float* __restrict__ Wk, const float* __restrict__ bk,
    const float* __restrict__ Wv, const float* __restrict__ bv,
    const float* __restrict__ Wp, ushort* __restrict__ Wpb,
    ushort* __restrict__ qb, ushort* __restrict__ kb, ushort* __restrict__ vb)
{
    __shared__ ushort tile[64 * QTP];   // ~33 KB

    const int t = threadIdx.x;
    const int wave = t >> 6;                 // 0..9 = mt
    const int lane = t & 63;
    const int l15 = lane & 15, qd = lane >> 4;
    const int b = blockIdx.y;
    const int n0 = blockIdx.x * 64;
    const int mt = wave;

    // ---- (a) Wp -> Wpb frag-native conversion (batch-0 blocks only) ----
    const int bid = blockIdx.y * gridDim.x + blockIdx.x;
    if (bid < 64 && t < 256) {
        const int e = (bid * 256 + t) * 4;   // 64 blocks * 1024 = 256*256
        const int row = e >> 8, col = e & 255;
        const floatx4 w = *(const floatx4*)(Wp + (size_t)row * CC + col);
        int2 d;
        d.x = pk_trunc(w[0], w[1]);
        d.y = pk_trunc(w[2], w[3]);
        // Wpb frag-native: [col>>3][row][col&7]; col&7 in {0,4} -> int2 fits
        *(int2*)(Wpb + (size_t)(col >> 3) * (CC * 8) + row * 8 + (col & 7)) = d;
    }

    // ---- (b) stage x slice -> LDS bf16 [n][c], 512 threads (2 passes ea.) ----
    if (t < 512) {
        const int tt = t & 255;
        const int cl = (tt >> 4) * 4;   // 4 c-rows per thread
        const int nl = (tt & 15) * 4;   // 4 n-cols per thread
        const int pb = (t >> 8) * 2;    // threads 0-255 -> passes 0,1; 256-511 -> 2,3
        #pragma unroll
        for (int pp = 0; pp < 2; ++pp) {
            const int cp = (pb + pp) * 64;
            const float* src = x + ((size_t)b * CC + cp + cl) * NN + n0 + nl;
            floatx4 v[4];
            #pragma unroll
            for (int i = 0; i < 4; ++i) v[i] = *(const floatx4*)(src + (size_t)i * NN);
            #pragma unroll
            for (int j = 0; j < 4; ++j) {
                *(int*)&tile[(nl + j) * QTP + cp + cl]     = pk_trunc(v[0][j], v[1][j]);
                *(int*)&tile[(nl + j) * QTP + cp + cl + 2] = pk_trunc(v[2][j], v[3][j]);
            }
        }
    }
    __syncthreads();

    // ---- (c) per-wave GEMM: A = W rows (fp32, converted in-register) ----
    const float* wr[2];
    if (mt == 0) {
        wr[0] = Wq + (size_t)l15 * CC;
        wr[1] = Wq + (size_t)(16 + l15) * CC;
    } else if (mt == 1) {
        wr[0] = Wk + (size_t)l15 * CC;
        wr[1] = Wk + (size_t)(16 + l15) * CC;
    } else {
        wr[0] = Wv + (size_t)((mt - 2) * 32 + l15) * CC;
        wr[1] = Wv + (size_t)((mt - 2) * 32 + 16 + l15) * CC;
    }

    floatx4 z = {0.f, 0.f, 0.f, 0.f};
    floatx4 acc[2][4];   // [fm][fn]: 32 o x 64 n
    #pragma unroll
    for (int fm = 0; fm < 2; ++fm)
        #pragma unroll
        for (int fn = 0; fn < 4; ++fn) acc[fm][fn] = z;

    #pragma unroll
    for (int k0 = 0; k0 < CC; k0 += 32) {
        short8 af[2], bfr[4];
        #pragma unroll
        for (int f = 0; f < 2; ++f) {
            const float* p = wr[f] + k0 + qd * 8;
            float w[8];
            #pragma unroll
            for (int j = 0; j < 8; ++j) w[j] = p[j];
            if (mt == 0) {
                #pragma unroll
                for (int j = 0; j < 8; ++j) w[j] *= SCALEF;
            }
            intx4 d;
            d[0] = pk_trunc(w[0], w[1]); d[1] = pk_trunc(w[2], w[3]);
            d[2] = pk_trunc(w[4], w[5]); d[3] = pk_trunc(w[6], w[7]);
            af[f] = __builtin_bit_cast(short8, d);
        }
        #pragma unroll
        for (int fn = 0; fn < 4; ++fn)
            bfr[fn] = *(const short8*)&tile[(fn * 16 + l15) * QTP + k0 + qd * 8];
        #pragma unroll
        for (int fm = 0; fm < 2; ++fm)
            #pragma unroll
            for (int fn = 0; fn < 4; ++fn)
                acc[fm][fn] = __builtin_amdgcn_mfma_f32_16x16x32_bf16(af[fm], bfr[fn], acc[fm][fn], 0, 0, 0);
    }

    // ---- store (R10-verbatim layouts) ----
    #pragma unroll
    for (int fm = 0; fm < 2; ++fm) {
        const int o0 = fm * 16 + qd * 4;
        if (mt == 0) {
            const floatx4 bb = *(const floatx4*)(bq + o0);
            #pragma unroll
            for (int fn = 0; fn < 4; ++fn) {
                ushort4 h;
                h.x = f2bf(acc[fm][fn][0] + bb[0] * SCALEF);
                h.y = f2bf(acc[fm][fn][1] + bb[1] * SCALEF);
                h.z = f2bf(acc[fm][fn][2] + bb[2] * SCALEF);
                h.w = f2bf(acc[fm][fn][3] + bb[3] * SCALEF);
                *(ushort4*)(qb + ((size_t)b * NN + n0 + fn * 16 + l15) * DD + o0) = h;
            }
        } else if (mt == 1) {
            const floatx4 bb = *(const floatx4*)(bk + o0);
            #pragma unroll
            for (int fn = 0; fn < 4; ++fn) {
                ushort4 h;
                h.x = f2bf(acc[fm][fn][0] + bb[0]);
                h.y = f2bf(acc[fm][fn][1] + bb[1]);
                h.z = f2bf(acc[fm][fn][2] + bb[2]);
                h.w = f2bf(acc[fm][fn][3] + bb[3]);
                // kb frag layout: [(n>>4)][d>>3][n&15][d&7]
                *(ushort4*)(kb + (size_t)b * NN * DD
                                 + (size_t)(n0 / 16 + fn) * 512
                                 + (fm * 2 + (qd >> 1)) * 128
                                 + l15 * 8 + (qd & 1) * 4) = h;
            }
        } else {
            const int oc0 = (mt - 2) * 32 + o0;
            const floatx4 bb = *(const floatx4*)(bv + oc0);
            #pragma unroll
            for (int r = 0; r < 4; ++r)
                #pragma unroll
                for (int fn = 0; fn < 4; ++fn)
                    // vb frag layout: [(k>>4)][c][k&15]
                    vb[(size_t)b * CC * NN
                       + (size_t)(n0 / 16 + fn) * (CC * 16)
                       + (oc0 + r) * 16 + l15] = f2bf(acc[fm][fn][r] + bb[r]);
        }
    }
}

// ---------------------------------------------------------------------------
// Kernel 2: MFMA flash attention — R10-VERBATIM main loop; ONLY the epilogue
// store changed: aoT now written FRAGMENT-NATIVE [b][c>>3][n][c&7] so proj's
// B-loads are contiguous (c = c0+cg*32+rq*8+hi*4+j -> c>>3 = c0/8+cg*4+rq,
// c&7 = hi*4+j; ushort4 8B-aligned).
// ---------------------------------------------------------------------------
__global__ __launch_bounds__(256, 2) void attn_mfma(
    const ushort* __restrict__ qb, const ushort* __restrict__ kb,
    const ushort* __restrict__ vb, ushort* __restrict__ aoT)
{
    __shared__ float red[2][8192];   // [slot][((qg*4+cg)*16 + r)*64 + lane]
    __shared__ float lred[2][64];    // [slot][qg*32 + (lane&31)]

    const int t = threadIdx.x;
    const int kh = t >> 6;               // key-quarter 0..3
    const int lane = t & 63;
    const int l31 = lane & 31;
    const bool hi = lane >= 32;
    const int hib = hi ? 8 : 0;
    const int slot = blockIdx.x;
    const int b = slot >> 1;
    const int qt = (slot & 1) * 32 + blockIdx.y;
    const int q0 = qt * 64;
    const int c0 = blockIdx.z * 128;

    // Q B-frags (qb layout unchanged): B[d][q], col=lane&31=q, k=d=hib+j
    short8 qf[2][2];
    #pragma unroll
    for (int qg = 0; qg < 2; ++qg)
        #pragma unroll
        for (int dh = 0; dh < 2; ++dh)
            qf[qg][dh] = *(const short8*)(qb + ((size_t)b * NN + q0 + qg * 32 + l31) * DD + dh * 16 + hib);

    // K frag-native: key = kh*1024 + kt*32 + l31, d = (frag)*16 + hib + j
    const ushort* krow = kb + (size_t)b * NN * DD + (size_t)kh * 64 * 512
                            + (l31 >> 4) * 512 + (l31 & 15) * 8 + hib * 16;  // hib*16 = hi*128
    // V frag-native: k = kh*1024 + kt*32 + k2*16 + hib + j, c = c0+cg*32+l31
    const ushort* vrow = vb + (size_t)b * CC * NN + (size_t)kh * 64 * (CC * 16)
                            + (c0 + l31) * 16 + hib;

    floatx16 z16 = {0.f,0.f,0.f,0.f,0.f,0.f,0.f,0.f,0.f,0.f,0.f,0.f,0.f,0.f,0.f,0.f};
    floatx16 acc[2][4];   // [qg][cg]: 64q x 128c wave tile
    #pragma unroll
    for (int qg = 0; qg < 2; ++qg)
        #pragma unroll
        for (int cg = 0; cg < 4; ++cg) acc[qg][cg] = z16;
    float lsum[2] = {0.f, 0.f};

    for (int kt = 0; kt < 32; ++kt) {
        short8 kf0 = *(const short8*)(krow);         // d 0..15
        short8 kf1 = *(const short8*)(krow + 256);   // d 16..31
        krow += 1024;                                // 2 key-blocks of 512
        short8 vf[4][2];
        #pragma unroll
        for (int cg = 0; cg < 4; ++cg)
            #pragma unroll
            for (int k2 = 0; k2 < 2; ++k2)
                vf[cg][k2] = *(const short8*)(vrow + cg * 512 + k2 * (CC * 16));
        vrow += 2 * (CC * 16);

        short8 ptB[2][2];   // [qg][k-half]: PV B-frags
        #pragma unroll
        for (int qg = 0; qg < 2; ++qg) {
            floatx16 s = __builtin_amdgcn_mfma_f32_32x32x16_bf16(kf0, qf[qg][0], z16, 0, 0, 0);
            s = __builtin_amdgcn_mfma_f32_32x32x16_bf16(kf1, qf[qg][1], s, 0, 0, 0);

            float e[16];
            #pragma unroll
            for (int r = 0; r < 16; ++r) e[r] = fast_exp2(s[r]);

            lsum[qg] += (((e[0]+e[1])+(e[2]+e[3]))+((e[4]+e[5])+(e[6]+e[7])))
                      + (((e[8]+e[9])+(e[10]+e[11]))+((e[12]+e[13])+(e[14]+e[15])));

            // keys 0-15 (B-frag k-half 0)
            int a0 = pk_trunc(e[0], e[1]),  b0 = pk_trunc(e[2], e[3]);
            int c0w = pk_trunc(e[4], e[5]), d0 = pk_trunc(e[6], e[7]);
            plswap(a0, c0w);
            plswap(b0, d0);
            intx4 f0 = {a0, b0, c0w, d0};
            ptB[qg][0] = __builtin_bit_cast(short8, f0);

            // keys 16-31 (B-frag k-half 1)
            int a1 = pk_trunc(e[8], e[9]),   b1 = pk_trunc(e[10], e[11]);
            int c1 = pk_trunc(e[12], e[13]), d1 = pk_trunc(e[14], e[15]);
            plswap(a1, c1);
            plswap(b1, d1);
            intx4 f1 = {a1, b1, c1, d1};
            ptB[qg][1] = __builtin_bit_cast(short8, f1);
        }

        __builtin_amdgcn_s_setprio(1);
        #pragma unroll
        for (int cg = 0; cg < 4; ++cg)
            #pragma unroll
            for (int qg = 0; qg < 2; ++qg) {
                acc[qg][cg] = __builtin_amdgcn_mfma_f32_32x32x16_bf16(vf[cg][0], ptB[qg][0], acc[qg][cg], 0, 0, 0);
                acc[qg][cg] = __builtin_amdgcn_mfma_f32_32x32x16_bf16(vf[cg][1], ptB[qg][1], acc[qg][cg], 0, 0, 0);
            }
        __builtin_amdgcn_s_setprio(0);
    }

    // fold partner-lane key-halves (each lane summed only its 16 of 32 keys)
    #pragma unroll
    for (int qg = 0; qg < 2; ++qg)
        lsum[qg] += __shfl(lsum[qg], lane ^ 32);

    // ---- reduction tree over key-quarters: (0+=1, 2+=3), then 0+=2 ----
    if (kh & 1) {
        const int s = kh >> 1;
        #pragma unroll
        for (int qg = 0; qg < 2; ++qg)
            #pragma unroll
            for (int cg = 0; cg < 4; ++cg)
                #pragma unroll
                for (int r = 0; r < 16; ++r)
                    red[s][((qg * 4 + cg) * 16 + r) * 64 + lane] = acc[qg][cg][r];
        if (!hi)
            #pragma unroll
            for (int qg = 0; qg < 2; ++qg) lred[s][qg * 32 + l31] = lsum[qg];
    }
    __syncthreads();
    if (!(kh & 1)) {
        const int s = kh >> 1;
        #pragma unroll
        for (int qg = 0; qg < 2; ++qg) {
            #pragma unroll
            for (int cg = 0; cg < 4; ++cg)
                #pragma unroll
                for (int r = 0; r < 16; ++r)
                    acc[qg][cg][r] += red[s][((qg * 4 + cg) * 16 + r) * 64 + lane];
            lsum[qg] += lred[s][qg * 32 + l31];
        }
    }
    __syncthreads();
    if (kh == 2) {
        #pragma unroll
        for (int qg = 0; qg < 2; ++qg)
            #pragma unroll
            for (int cg = 0; cg < 4; ++cg)
                #pragma unroll
                for (int r = 0; r < 16; ++r)
                    red[0][((qg * 4 + cg) * 16 + r) * 64 + lane] = acc[qg][cg][r];
        if (!hi)
            #pragma unroll
            for (int qg = 0; qg < 2; ++qg) lred[0][qg * 32 + l31] = lsum[qg];
    }
    __syncthreads();
    if (kh == 0) {
        #pragma unroll
        for (int qg = 0; qg < 2; ++qg) {
            #pragma unroll
            for (int cg = 0; cg < 4; ++cg)
                #pragma unroll
                for (int r = 0; r < 16; ++r)
                    acc[qg][cg][r] += red[0][((qg * 4 + cg) * 16 + r) * 64 + lane];
            lsum[qg] += lred[0][qg * 32 + l31];
        }
        // store: aoT2 frag-native [b][c>>3][n][c&7]; c = c0+cg*32+rq*8+hi*4
        #pragma unroll
        for (int qg = 0; qg < 2; ++qg) {
            const float inv = 1.0f / lsum[qg];
            const int n = q0 + qg * 32 + l31;
            ushort* dstb = aoT + (size_t)b * NN * CC;
            #pragma unroll
            for (int cg = 0; cg < 4; ++cg) {
                #pragma unroll
                for (int rq = 0; rq < 4; ++rq) {
                    ushort4 h;
                    h.x = f2bf(acc[qg][cg][rq * 4 + 0] * inv);
                    h.y = f2bf(acc[qg][cg][rq * 4 + 1] * inv);
                    h.z = f2bf(acc[qg][cg][rq * 4 + 2] * inv);
                    h.w = f2bf(acc[qg][cg][rq * 4 + 3] * inv);
                    *(ushort4*)(dstb + (size_t)(c0 / 8 + cg * 4 + rq) * (NN * 8)
                                     + (size_t)n * 8 + (hi ? 4 : 0)) = h;
                }
            }
        }
    }
}

// ---------------------------------------------------------------------------
// Kernel 3: MFMA output projection + residual — A and B loads now from
// FRAGMENT-NATIVE buffers (Wpb [c>>3][m][c&7], aoT [b][c>>3][n][c&7]):
// every load is a contiguous 256B-run pattern (was 512B-stride 4x-line
// gather on both operands).  Compute/epilogue unchanged.
// ---------------------------------------------------------------------------
__global__ __launch_bounds__(256) void proj_mfma(
    const ushort* __restrict__ aoT, const ushort* __restrict__ Wpb,
    const float* __restrict__ bp, const float* __restrict__ x,
    const float* __restrict__ gamma, float* __restrict__ out)
{
    const int t = threadIdx.x;
    const int wave = t >> 6;
    const int lane = t & 63;
    const int l15 = lane & 15;
    const int qd = lane >> 4;
    const int b = blockIdx.z;
    const int m0 = blockIdx.y * 32;
    const int n0 = blockIdx.x * 128 + wave * 32;

    floatx4 z = {0.f, 0.f, 0.f, 0.f};
    floatx4 acc[2][2];
    acc[0][0] = z; acc[0][1] = z; acc[1][0] = z; acc[1][1] = z;

    const ushort* ab = aoT + (size_t)b * NN * CC;

    #pragma unroll
    for (int k0 = 0; k0 < CC; k0 += 32) {
        const size_t cblk = (size_t)(k0 / 8 + qd);
        short8 af[2], bfr[2];
        af[0]  = *(const short8*)(Wpb + cblk * (CC * 8) + (m0 + l15) * 8);
        af[1]  = *(const short8*)(Wpb + cblk * (CC * 8) + (m0 + 16 + l15) * 8);
        bfr[0] = *(const short8*)(ab + cblk * (NN * 8) + (size_t)(n0 + l15) * 8);
        bfr[1] = *(const short8*)(ab + cblk * (NN * 8) + (size_t)(n0 + 16 + l15) * 8);
        #pragma unroll
        for (int fm = 0; fm < 2; ++fm)
            #pragma unroll
            for (int fn = 0; fn < 2; ++fn)
                acc[fm][fn] = __builtin_amdgcn_mfma_f32_16x16x32_bf16(af[fm], bfr[fn], acc[fm][fn], 0, 0, 0);
    }

    const float g = gamma[0];
    #pragma unroll
    for (int fm = 0; fm < 2; ++fm) {
        #pragma unroll
        for (int r = 0; r < 4; ++r) {
            int m = m0 + fm * 16 + qd * 4 + r;
            float bpv = bp[m];
            #pragma unroll
            for (int fn = 0; fn < 2; ++fn) {
                size_t addr = ((size_t)b * CC + m) * NN + n0 + fn * 16 + l15;
                out[addr] = fmaf(g, acc[fm][fn][r] + bpv, x[addr]);
            }
        }
    }
}

extern "C" void kernel_launch(void* const* d_in, const int* in_sizes, int n_in,
                              void* d_out, int out_size, void* d_ws, size_t ws_size,
                              hipStream_t stream)
{
    const float* x     = (const float*)d_in[0];
    const float* Wq    = (const float*)d_in[1];
    const float* bq    = (const float*)d_in[2];
    const float* Wk    = (const float*)d_in[3];
    const float* bk    = (const float*)d_in[4];
    const float* Wv    = (const float*)d_in[5];
    const float* bv    = (const float*)d_in[6];
    const float* Wp    = (const float*)d_in[7];
    const float* bp    = (const float*)d_in[8];
    const float* gamma = (const float*)d_in[9];
    float* out = (float*)d_out;

    ushort* qbw = (ushort*)d_ws;                        // B*N*32  bf16 = 1 MB
    ushort* kbw = qbw + (size_t)BB * NN * DD;           // B*N*32  bf16 = 1 MB (frag layout)
    ushort* vbw = kbw + (size_t)BB * NN * DD;           // B*C*N   bf16 = 8 MB (frag layout)
    ushort* aoT = vbw + (size_t)BB * CC * NN;           // B*N*C   bf16 = 8 MB (frag layout)
    ushort* Wpb = aoT + (size_t)BB * NN * CC;           // 256*256 bf16 = 128 KB (frag layout)

    qkv_fused<<<dim3(NN / 64, BB), 640, 0, stream>>>(x, Wq, bq, Wk, bk, Wv, bv, Wp, Wpb, qbw, kbw, vbw);
    attn_mfma<<<dim3(8, 32, 2), 256, 0, stream>>>(qbw, kbw, vbw, aoT);
    proj_mfma<<<dim3(NN / 128, CC / 32, BB), 256, 0, stream>>>(aoT, Wpb, bp, x, gamma, out);
}

// Round 13
// 150.332 us; speedup vs baseline: 1.7208x; 1.0169x over previous
//
#include <hip/hip_runtime.h>
#include <math.h>

#define BB 4
#define CC 256
#define DD 32
#define NN 4096

typedef __attribute__((ext_vector_type(8))) short short8;
typedef __attribute__((ext_vector_type(4))) float floatx4;
typedef __attribute__((ext_vector_type(16))) float floatx16;
typedef __attribute__((ext_vector_type(4))) int intx4;
typedef __attribute__((ext_vector_type(2))) int intx2;

#define SCALEF (0.17677669529663687f * 1.4426950408889634f)  // 1/sqrt(32)*log2(e)

// float -> bf16 round-to-nearest-even
__device__ __forceinline__ ushort f2bf(float f) {
    unsigned int u = __builtin_bit_cast(unsigned int, f);
    u += 0x7FFFu + ((u >> 16) & 1u);
    return (ushort)(u >> 16);
}
// pack two floats' bf16 truncations into one dword with a single v_perm_b32
__device__ __forceinline__ int pk_trunc(float a, float b) {
    return (int)__builtin_amdgcn_perm(__builtin_bit_cast(unsigned, b),
                                      __builtin_bit_cast(unsigned, a),
                                      0x07060302u);
}
__device__ __forceinline__ float fast_exp2(float x) {
#if __has_builtin(__builtin_amdgcn_exp2f)
    return __builtin_amdgcn_exp2f(x);
#else
    return exp2f(x);
#endif
}
// permlane32_swap: a'.hi <- b.lo, b'.lo <- a.hi (lo/hi = 32-lane halves)
__device__ __forceinline__ void plswap(int& a, int& b) {
#if __has_builtin(__builtin_amdgcn_permlane32_swap)
    intx2 r = __builtin_amdgcn_permlane32_swap(a, b, false, false);
    a = r[0]; b = r[1];
#else
    const int lane = threadIdx.x & 63;
    const bool hi = lane >= 32;
    int a2 = __shfl(a, lane ^ 32);
    int b2 = __shfl(b, lane ^ 32);
    int na = hi ? b2 : a;
    int nb = hi ? b : a2;
    a = na; b = nb;
#endif
}

// ---------------------------------------------------------------------------
// Kernel 1: FUSED transpose + QKV projection (R12-VERBATIM).
// Outputs: qb linear; kb/vb MFMA-fragment-native; Wpb frag-native
// [c>>3][m][c&7] (consumed by attn_proj's proj phase).
// ---------------------------------------------------------------------------
#define QTP 264   // LDS pitch in ushorts (132 dwords; stride 4 banks -> <=2-way)
__global__ __launch_bounds__(640) void qkv_fused(
    const float* __restrict__ x,
    const float* __restrict__ Wq, const float* __restrict__ bq,
    const float* __restrict__ Wk, const float* __restrict__ bk,
    const float* __restrict__ Wv, const float* __restrict__ bv,
    const float* __restrict__ Wp, ushort* __restrict__ Wpb,
    ushort* __restrict__ qb, ushort* __restrict__ kb, ushort* __restrict__ vb)
{
    __shared__ ushort tile[64 * QTP];   // ~33 KB

    const int t = threadIdx.x;
    const int wave = t >> 6;                 // 0..9 = mt
    const int lane = t & 63;
    const int l15 = lane & 15, qd = lane >> 4;
    const int b = blockIdx.y;
    const int n0 = blockIdx.x * 64;
    const int mt = wave;

    // ---- (a) Wp -> Wpb frag-native conversion (batch-0 blocks only) ----
    const int bid = blockIdx.y * gridDim.x + blockIdx.x;
    if (bid < 64 && t < 256) {
        const int e = (bid * 256 + t) * 4;   // 64 blocks * 1024 = 256*256
        const int row = e >> 8, col = e & 255;
        const floatx4 w = *(const floatx4*)(Wp + (size_t)row * CC + col);
        int2 d;
        d.x = pk_trunc(w[0], w[1]);
        d.y = pk_trunc(w[2], w[3]);
        // Wpb frag-native: [col>>3][row][col&7]; col&7 in {0,4} -> int2 fits
        *(int2*)(Wpb + (size_t)(col >> 3) * (CC * 8) + row * 8 + (col & 7)) = d;
    }

    // ---- (b) stage x slice -> LDS bf16 [n][c], 512 threads (2 passes ea.) ----
    if (t < 512) {
        const int tt = t & 255;
        const int cl = (tt >> 4) * 4;   // 4 c-rows per thread
        const int nl = (tt & 15) * 4;   // 4 n-cols per thread
        const int pb = (t >> 8) * 2;    // threads 0-255 -> passes 0,1; 256-511 -> 2,3
        #pragma unroll
        for (int pp = 0; pp < 2; ++pp) {
            const int cp = (pb + pp) * 64;
            const float* src = x + ((size_t)b * CC + cp + cl) * NN + n0 + nl;
            floatx4 v[4];
            #pragma unroll
            for (int i = 0; i < 4; ++i) v[i] = *(const floatx4*)(src + (size_t)i * NN);
            #pragma unroll
            for (int j = 0; j < 4; ++j) {
                *(int*)&tile[(nl + j) * QTP + cp + cl]     = pk_trunc(v[0][j], v[1][j]);
                *(int*)&tile[(nl + j) * QTP + cp + cl + 2] = pk_trunc(v[2][j], v[3][j]);
            }
        }
    }
    __syncthreads();

    // ---- (c) per-wave GEMM: A = W rows (fp32, converted in-register) ----
    const float* wr[2];
    if (mt == 0) {
        wr[0] = Wq + (size_t)l15 * CC;
        wr[1] = Wq + (size_t)(16 + l15) * CC;
    } else if (mt == 1) {
        wr[0] = Wk + (size_t)l15 * CC;
        wr[1] = Wk + (size_t)(16 + l15) * CC;
    } else {
        wr[0] = Wv + (size_t)((mt - 2) * 32 + l15) * CC;
        wr[1] = Wv + (size_t)((mt - 2) * 32 + 16 + l15) * CC;
    }

    floatx4 z = {0.f, 0.f, 0.f, 0.f};
    floatx4 acc[2][4];   // [fm][fn]: 32 o x 64 n
    #pragma unroll
    for (int fm = 0; fm < 2; ++fm)
        #pragma unroll
        for (int fn = 0; fn < 4; ++fn) acc[fm][fn] = z;

    #pragma unroll
    for (int k0 = 0; k0 < CC; k0 += 32) {
        short8 af[2], bfr[4];
        #pragma unroll
        for (int f = 0; f < 2; ++f) {
            const float* p = wr[f] + k0 + qd * 8;
            float w[8];
            #pragma unroll
            for (int j = 0; j < 8; ++j) w[j] = p[j];
            if (mt == 0) {
                #pragma unroll
                for (int j = 0; j < 8; ++j) w[j] *= SCALEF;
            }
            intx4 d;
            d[0] = pk_trunc(w[0], w[1]); d[1] = pk_trunc(w[2], w[3]);
            d[2] = pk_trunc(w[4], w[5]); d[3] = pk_trunc(w[6], w[7]);
            af[f] = __builtin_bit_cast(short8, d);
        }
        #pragma unroll
        for (int fn = 0; fn < 4; ++fn)
            bfr[fn] = *(const short8*)&tile[(fn * 16 + l15) * QTP + k0 + qd * 8];
        #pragma unroll
        for (int fm = 0; fm < 2; ++fm)
            #pragma unroll
            for (int fn = 0; fn < 4; ++fn)
                acc[fm][fn] = __builtin_amdgcn_mfma_f32_16x16x32_bf16(af[fm], bfr[fn], acc[fm][fn], 0, 0, 0);
    }

    // ---- store (R10-verbatim layouts) ----
    #pragma unroll
    for (int fm = 0; fm < 2; ++fm) {
        const int o0 = fm * 16 + qd * 4;
        if (mt == 0) {
            const floatx4 bb = *(const floatx4*)(bq + o0);
            #pragma unroll
            for (int fn = 0; fn < 4; ++fn) {
                ushort4 h;
                h.x = f2bf(acc[fm][fn][0] + bb[0] * SCALEF);
                h.y = f2bf(acc[fm][fn][1] + bb[1] * SCALEF);
                h.z = f2bf(acc[fm][fn][2] + bb[2] * SCALEF);
                h.w = f2bf(acc[fm][fn][3] + bb[3] * SCALEF);
                *(ushort4*)(qb + ((size_t)b * NN + n0 + fn * 16 + l15) * DD + o0) = h;
            }
        } else if (mt == 1) {
            const floatx4 bb = *(const floatx4*)(bk + o0);
            #pragma unroll
            for (int fn = 0; fn < 4; ++fn) {
                ushort4 h;
                h.x = f2bf(acc[fm][fn][0] + bb[0]);
                h.y = f2bf(acc[fm][fn][1] + bb[1]);
                h.z = f2bf(acc[fm][fn][2] + bb[2]);
                h.w = f2bf(acc[fm][fn][3] + bb[3]);
                // kb frag layout: [(n>>4)][d>>3][n&15][d&7]
                *(ushort4*)(kb + (size_t)b * NN * DD
                                 + (size_t)(n0 / 16 + fn) * 512
                                 + (fm * 2 + (qd >> 1)) * 128
                                 + l15 * 8 + (qd & 1) * 4) = h;
            }
        } else {
            const int oc0 = (mt - 2) * 32 + o0;
            const floatx4 bb = *(const floatx4*)(bv + oc0);
            #pragma unroll
            for (int r = 0; r < 4; ++r)
                #pragma unroll
                for (int fn = 0; fn < 4; ++fn)
                    // vb frag layout: [(k>>4)][c][k&15]
                    vb[(size_t)b * CC * NN
                       + (size_t)(n0 / 16 + fn) * (CC * 16)
                       + (oc0 + r) * 16 + l15] = f2bf(acc[fm][fn][r] + bb[r]);
        }
    }
}

// ---------------------------------------------------------------------------
// Kernel 2: FUSED flash attention + output projection + residual.
// Grid (8,32) = 256 blocks = 1/CU, 8 waves (512 thr).  Wave (kh=w&3, ch=w>>2)
// runs the R12-VERBATIM attn main loop for c-half ch (per-wave work and total
// redundancy identical to the old z=2 grid).  kh-reduction tree per ch
// (red[ch][s], 128 KB).  The two kh==0 waves write the normalized ao tile
// (64n x 256c bf16) into LDS frag-native [c>>3][n][c&7] (aliased over red,
// extra barrier protects the alias), then ALL 8 waves compute the proj GEMM
// (wave w owns m-rows w*32..w*32+31; A = Wpb frag-native global, B = ao LDS)
// and write out = x + gamma*(Wp@ao + bp) directly.  Eliminates the proj
// dispatch and the aoT global round-trip (8 MB write + ~64 MB L2 re-read).
// ---------------------------------------------------------------------------
__global__ __launch_bounds__(512, 2) void attn_proj(
    const ushort* __restrict__ qb, const ushort* __restrict__ kb,
    const ushort* __restrict__ vb, const ushort* __restrict__ Wpb,
    const float* __restrict__ bp, const float* __restrict__ x,
    const float* __restrict__ gamma, float* __restrict__ out)
{
    __shared__ float red[2][2][8192];   // [ch][slot][((qg*4+cg)*16 + r)*64 + lane]
    __shared__ float lred[2][2][64];    // [ch][slot][qg*32 + (lane&31)]
    ushort* ao_u = (ushort*)&red[0][0][0];   // 32 KB alias: ao[c>>3][n][c&7]

    const int t = threadIdx.x;
    const int w = t >> 6;                // wave 0..7
    const int kh = w & 3;                // key-quarter
    const int ch = w >> 2;               // c-half 0..1
    const int lane = t & 63;
    const int l31 = lane & 31;
    const bool hi = lane >= 32;
    const int hib = hi ? 8 : 0;
    const int slot = blockIdx.x;
    const int b = slot >> 1;
    const int qt = (slot & 1) * 32 + blockIdx.y;
    const int q0 = qt * 64;
    const int c0 = ch * 128;

    // Q B-frags: B[d][q], col=lane&31=q, k=d=hib+j
    short8 qf[2][2];
    #pragma unroll
    for (int qg = 0; qg < 2; ++qg)
        #pragma unroll
        for (int dh = 0; dh < 2; ++dh)
            qf[qg][dh] = *(const short8*)(qb + ((size_t)b * NN + q0 + qg * 32 + l31) * DD + dh * 16 + hib);

    // K frag-native: key = kh*1024 + kt*32 + l31, d = (frag)*16 + hib + j
    const ushort* krow = kb + (size_t)b * NN * DD + (size_t)kh * 64 * 512
                            + (l31 >> 4) * 512 + (l31 & 15) * 8 + hib * 16;  // hib*16 = hi*128
    // V frag-native: k = kh*1024 + kt*32 + k2*16 + hib + j, c = c0+cg*32+l31
    const ushort* vrow = vb + (size_t)b * CC * NN + (size_t)kh * 64 * (CC * 16)
                            + (c0 + l31) * 16 + hib;

    floatx16 z16 = {0.f,0.f,0.f,0.f,0.f,0.f,0.f,0.f,0.f,0.f,0.f,0.f,0.f,0.f,0.f,0.f};
    floatx16 acc[2][4];   // [qg][cg]: 64q x 128c wave tile
    #pragma unroll
    for (int qg = 0; qg < 2; ++qg)
        #pragma unroll
        for (int cg = 0; cg < 4; ++cg) acc[qg][cg] = z16;
    float lsum[2] = {0.f, 0.f};

    for (int kt = 0; kt < 32; ++kt) {
        short8 kf0 = *(const short8*)(krow);         // d 0..15
        short8 kf1 = *(const short8*)(krow + 256);   // d 16..31
        krow += 1024;                                // 2 key-blocks of 512
        short8 vf[4][2];
        #pragma unroll
        for (int cg = 0; cg < 4; ++cg)
            #pragma unroll
            for (int k2 = 0; k2 < 2; ++k2)
                vf[cg][k2] = *(const short8*)(vrow + cg * 512 + k2 * (CC * 16));
        vrow += 2 * (CC * 16);

        short8 ptB[2][2];   // [qg][k-half]: PV B-frags
        #pragma unroll
        for (int qg = 0; qg < 2; ++qg) {
            floatx16 s = __builtin_amdgcn_mfma_f32_32x32x16_bf16(kf0, qf[qg][0], z16, 0, 0, 0);
            s = __builtin_amdgcn_mfma_f32_32x32x16_bf16(kf1, qf[qg][1], s, 0, 0, 0);

            float e[16];
            #pragma unroll
            for (int r = 0; r < 16; ++r) e[r] = fast_exp2(s[r]);

            lsum[qg] += (((e[0]+e[1])+(e[2]+e[3]))+((e[4]+e[5])+(e[6]+e[7])))
                      + (((e[8]+e[9])+(e[10]+e[11]))+((e[12]+e[13])+(e[14]+e[15])));

            // keys 0-15 (B-frag k-half 0)
            int a0 = pk_trunc(e[0], e[1]),  b0 = pk_trunc(e[2], e[3]);
            int c0w = pk_trunc(e[4], e[5]), d0 = pk_trunc(e[6], e[7]);
            plswap(a0, c0w);
            plswap(b0, d0);
            intx4 f0 = {a0, b0, c0w, d0};
            ptB[qg][0] = __builtin_bit_cast(short8, f0);

            // keys 16-31 (B-frag k-half 1)
            int a1 = pk_trunc(e[8], e[9]),   b1 = pk_trunc(e[10], e[11]);
            int c1 = pk_trunc(e[12], e[13]), d1 = pk_trunc(e[14], e[15]);
            plswap(a1, c1);
            plswap(b1, d1);
            intx4 f1 = {a1, b1, c1, d1};
            ptB[qg][1] = __builtin_bit_cast(short8, f1);
        }

        __builtin_amdgcn_s_setprio(1);
        #pragma unroll
        for (int cg = 0; cg < 4; ++cg)
            #pragma unroll
            for (int qg = 0; qg < 2; ++qg) {
                acc[qg][cg] = __builtin_amdgcn_mfma_f32_32x32x16_bf16(vf[cg][0], ptB[qg][0], acc[qg][cg], 0, 0, 0);
                acc[qg][cg] = __builtin_amdgcn_mfma_f32_32x32x16_bf16(vf[cg][1], ptB[qg][1], acc[qg][cg], 0, 0, 0);
            }
        __builtin_amdgcn_s_setprio(0);
    }

    // fold partner-lane key-halves (each lane summed only its 16 of 32 keys)
    #pragma unroll
    for (int qg = 0; qg < 2; ++qg)
        lsum[qg] += __shfl(lsum[qg], lane ^ 32);

    // ---- reduction tree over key-quarters (within each ch) ----
    if (kh & 1) {
        const int s = kh >> 1;
        #pragma unroll
        for (int qg = 0; qg < 2; ++qg)
            #pragma unroll
            for (int cg = 0; cg < 4; ++cg)
                #pragma unroll
                for (int r = 0; r < 16; ++r)
                    red[ch][s][((qg * 4 + cg) * 16 + r) * 64 + lane] = acc[qg][cg][r];
        if (!hi)
            #pragma unroll
            for (int qg = 0; qg < 2; ++qg) lred[ch][s][qg * 32 + l31] = lsum[qg];
    }
    __syncthreads();
    if (!(kh & 1)) {
        const int s = kh >> 1;
        #pragma unroll
        for (int qg = 0; qg < 2; ++qg) {
            #pragma unroll
            for (int cg = 0; cg < 4; ++cg)
                #pragma unroll
                for (int r = 0; r < 16; ++r)
                    acc[qg][cg][r] += red[ch][s][((qg * 4 + cg) * 16 + r) * 64 + lane];
            lsum[qg] += lred[ch][s][qg * 32 + l31];
        }
    }
    __syncthreads();
    if (kh == 2) {
        #pragma unroll
        for (int qg = 0; qg < 2; ++qg)
            #pragma unroll
            for (int cg = 0; cg < 4; ++cg)
                #pragma unroll
                for (int r = 0; r < 16; ++r)
                    red[ch][0][((qg * 4 + cg) * 16 + r) * 64 + lane] = acc[qg][cg][r];
        if (!hi)
            #pragma unroll
            for (int qg = 0; qg < 2; ++qg) lred[ch][0][qg * 32 + l31] = lsum[qg];
    }
    __syncthreads();
    if (kh == 0) {
        #pragma unroll
        for (int qg = 0; qg < 2; ++qg) {
            #pragma unroll
            for (int cg = 0; cg < 4; ++cg)
                #pragma unroll
                for (int r = 0; r < 16; ++r)
                    acc[qg][cg][r] += red[ch][0][((qg * 4 + cg) * 16 + r) * 64 + lane];
            lsum[qg] += lred[ch][0][qg * 32 + l31];
        }
    }
    __syncthreads();   // all red reads done before ao alias is written

    // ---- kh==0 waves write normalized ao tile to LDS (frag-native) ----
    if (kh == 0) {
        #pragma unroll
        for (int qg = 0; qg < 2; ++qg) {
            const float inv = 1.0f / lsum[qg];
            const int nl = qg * 32 + l31;
            #pragma unroll
            for (int cg = 0; cg < 4; ++cg) {
                #pragma unroll
                for (int rq = 0; rq < 4; ++rq) {
                    ushort4 h;
                    h.x = f2bf(acc[qg][cg][rq * 4 + 0] * inv);
                    h.y = f2bf(acc[qg][cg][rq * 4 + 1] * inv);
                    h.z = f2bf(acc[qg][cg][rq * 4 + 2] * inv);
                    h.w = f2bf(acc[qg][cg][rq * 4 + 3] * inv);
                    *(ushort4*)&ao_u[(((ch * 16 + cg * 4 + rq) * 64) + nl) * 8 + (hi ? 4 : 0)] = h;
                }
            }
        }
    }
    __syncthreads();   // ao visible to all waves

    // ---- proj phase: wave w owns m-rows w*32..w*32+31, all 64 n ----
    const int m0w = w * 32;
    floatx16 pacc0 = z16, pacc1 = z16;
    #pragma unroll
    for (int kc = 0; kc < 16; ++kc) {
        const int cb = kc * 2 + (hi ? 1 : 0);
        short8 af  = *(const short8*)(Wpb + (size_t)cb * (CC * 8) + (m0w + l31) * 8);
        short8 bf0 = *(const short8*)&ao_u[(cb * 64 + l31) * 8];
        short8 bf1 = *(const short8*)&ao_u[(cb * 64 + 32 + l31) * 8];
        pacc0 = __builtin_amdgcn_mfma_f32_32x32x16_bf16(af, bf0, pacc0, 0, 0, 0);
        pacc1 = __builtin_amdgcn_mfma_f32_32x32x16_bf16(af, bf1, pacc1, 0, 0, 0);
    }
    const float g = gamma[0];
    #pragma unroll
    for (int r = 0; r < 16; ++r) {
        const int m = m0w + (r & 3) + 8 * (r >> 2) + (hi ? 4 : 0);
        const float bpv = bp[m];
        const size_t a0 = ((size_t)b * CC + m) * NN + q0 + l31;
        out[a0] = fmaf(g, pacc0[r] + bpv, x[a0]);
        const size_t a1 = a0 + 32;
        out[a1] = fmaf(g, pacc1[r] + bpv, x[a1]);
    }
}

extern "C" void kernel_launch(void* const* d_in, const int* in_sizes, int n_in,
                              void* d_out, int out_size, void* d_ws, size_t ws_size,
                              hipStream_t stream)
{
    const float* x     = (const float*)d_in[0];
    const float* Wq    = (const float*)d_in[1];
    const float* bq    = (const float*)d_in[2];
    const float* Wk    = (const float*)d_in[3];
    const float* bk    = (const float*)d_in[4];
    const float* Wv    = (const float*)d_in[5];
    const float* bv    = (const float*)d_in[6];
    const float* Wp    = (const float*)d_in[7];
    const float* bp    = (const float*)d_in[8];
    const float* gamma = (const float*)d_in[9];
    float* out = (float*)d_out;

    ushort* qbw = (ushort*)d_ws;                        // B*N*32  bf16 = 1 MB
    ushort* kbw = qbw + (size_t)BB * NN * DD;           // B*N*32  bf16 = 1 MB (frag layout)
    ushort* vbw = kbw + (size_t)BB * NN * DD;           // B*C*N   bf16 = 8 MB (frag layout)
    ushort* Wpb = vbw + (size_t)BB * CC * NN;           // 256*256 bf16 = 128 KB (frag layout)

    qkv_fused<<<dim3(NN / 64, BB), 640, 0, stream>>>(x, Wq, bq, Wk, bk, Wv, bv, Wp, Wpb, qbw, kbw, vbw);
    attn_proj<<<dim3(8, 32), 512, 0, stream>>>(qbw, kbw, vbw, Wpb, bp, x, gamma, out);
}